// Round 7
// baseline (328.730 us; speedup 1.0000x reference)
//
#include <hip/hip_runtime.h>

#define H 128
typedef unsigned int uint32;
typedef unsigned short ushort16;
typedef __attribute__((ext_vector_type(8))) short bf16x8;
typedef __attribute__((ext_vector_type(4))) float f32x4;

#define LSTRIDE 136   // LDS row stride in bf16 elems: 272B, 16B-aligned, 2-way bank (free)

static __device__ __forceinline__ ushort16 f2bf(float f){
  uint32 u = __float_as_uint(f);
  uint32 r = (u + 0x7fff + ((u >> 16) & 1)) >> 16;   // RNE bf16 (finite values)
  return (ushort16)r;
}
static __device__ __forceinline__ float bflo(uint32 u){ return __uint_as_float(u << 16); }
static __device__ __forceinline__ float bfhi(uint32 u){ return __uint_as_float(u & 0xffff0000u); }

// rank[e] = position of edge e within its dst bucket; deg counts real in-edges
__global__ __launch_bounds__(256) void k_count_rank(const int* __restrict__ dst, int E,
                                                    int* __restrict__ deg, int* __restrict__ rank){
  int i = blockIdx.x*256 + threadIdx.x;
  if (i < E) rank[i] = atomicAdd(&deg[dst[i]], 1);
}

// ---- multi-block exclusive scan of (deg+1) -> offsets, plus dinv = rsqrt(deg+1) ----
__global__ __launch_bounds__(256) void k_scan1(const int* __restrict__ deg, int n,
      int* __restrict__ offsets, int* __restrict__ bsum, float* __restrict__ dinv){
  __shared__ int sh[256];
  int b = blockIdx.x, t = threadIdx.x;
  int base = b*1024 + t*4;
  bool i0 = base+0 < n, i1 = base+1 < n, i2 = base+2 < n, i3 = base+3 < n;
  int d0=0,d1=0,d2=0,d3=0;
  if (i3){ int4 v = *(const int4*)&deg[base]; d0=v.x; d1=v.y; d2=v.z; d3=v.w; }
  else {
    if (i0) d0 = deg[base+0];
    if (i1) d1 = deg[base+1];
    if (i2) d2 = deg[base+2];
  }
  int e0 = i0? d0+1:0, e1 = i1? d1+1:0, e2 = i2? d2+1:0, e3 = i3? d3+1:0;   // +1 self-loop
  sh[t] = e0+e1+e2+e3;
  __syncthreads();
  for (int off=1; off<256; off<<=1){
    int v = sh[t];
    int add = (t>=off)? sh[t-off] : 0;
    __syncthreads();
    sh[t] = v+add;
    __syncthreads();
  }
  int o0 = (t==0)?0:sh[t-1];
  int o1 = o0+e0, o2 = o1+e1, o3 = o2+e2;
  if (i0){ offsets[base+0]=o0; dinv[base+0]=rsqrtf((float)(d0+1)); }
  if (i1){ offsets[base+1]=o1; dinv[base+1]=rsqrtf((float)(d1+1)); }
  if (i2){ offsets[base+2]=o2; dinv[base+2]=rsqrtf((float)(d2+1)); }
  if (i3){ offsets[base+3]=o3; dinv[base+3]=rsqrtf((float)(d3+1)); }
  if (t==255) bsum[b] = sh[255];
}

__global__ __launch_bounds__(256) void k_scan2(int* __restrict__ bsum, int B, int n, int* __restrict__ offsets){
  __shared__ int sh[256];
  int t = threadIdx.x;
  sh[t] = (t<B)? bsum[t] : 0;
  __syncthreads();
  for (int off=1; off<256; off<<=1){
    int v = sh[t];
    int add = (t>=off)? sh[t-off] : 0;
    __syncthreads();
    sh[t] = v+add;
    __syncthreads();
  }
  if (t<B) bsum[t] = (t==0)?0:sh[t-1];
  if (t==255) offsets[n] = sh[255];
}

__global__ __launch_bounds__(256) void k_scan3(int* __restrict__ offsets, int n, const int* __restrict__ bsum){
  int b = blockIdx.x, t = threadIdx.x;
  int add = bsum[b];
  int base = b*1024 + t*4;
  if (base+3 < n){
    int4 v = *(int4*)&offsets[base];
    v.x+=add; v.y+=add; v.z+=add; v.w+=add;
    *(int4*)&offsets[base] = v;
  } else {
    #pragma unroll
    for (int k=0;k<4;k++){ int i=base+k; if (i<n) offsets[i]+=add; }
  }
}

// atomic-free CSR fill: real edge e -> slot offsets[dst]+1+rank[e]; self-loop at slot offsets[i]
__global__ __launch_bounds__(256) void k_fill2(const int* __restrict__ src, const int* __restrict__ dst,
            int E, int n, const int* __restrict__ offsets, const int* __restrict__ rank,
            int* __restrict__ csr_src){
  int i = blockIdx.x*256 + threadIdx.x;
  if (i < E){
    csr_src[offsets[dst[i]] + 1 + rank[i]] = src[i];
  } else if (i < E + n){
    int j = i - E;
    csr_src[offsets[j]] = j;
  }
}

// y0[i] = dinv[i] * pos[i]  (padded float4)
__global__ __launch_bounds__(256) void k_prescale(const float* __restrict__ pos, const float* __restrict__ dinv,
                                                  float4* __restrict__ y0, int n){
  int i = blockIdx.x*256 + threadIdx.x;
  if (i < n){
    float d = dinv[i];
    y0[i] = make_float4(pos[3*i]*d, pos[3*i+1]*d, pos[3*i+2]*d, 0.f);
  }
}

// a1[d] = dinv[d] * sum_src y0[src]
__global__ __launch_bounds__(256) void k_agg3(const float4* __restrict__ y0, const int* __restrict__ offsets,
      const int* __restrict__ csr_src, const float* __restrict__ dinv, float4* __restrict__ a1, int n){
  int node = blockIdx.x*256 + threadIdx.x;
  if (node >= n) return;
  int lo = offsets[node], hi = offsets[node+1];
  float x=0.f, y=0.f, z=0.f;
  int e = lo;
  for (; e+2 <= hi; e += 2){
    int s0 = csr_src[e], s1 = csr_src[e+1];
    float4 v0 = y0[s0], v1 = y0[s1];
    x += v0.x + v1.x; y += v0.y + v1.y; z += v0.z + v1.z;
  }
  if (e < hi){ float4 v = y0[csr_src[e]]; x += v.x; y += v.y; z += v.z; }
  float dn = dinv[node];
  a1[node] = make_float4(x*dn, y*dn, z*dn, 0.f);
}

// y1[node,f] = bf16( dinv[node] * relu(a1[node] . W1[:,f] + b1[f]) )
__global__ __launch_bounds__(128) void k_dense1(const float4* __restrict__ a1, const float* __restrict__ W1,
      const float* __restrict__ b1, const float* __restrict__ dinv, ushort16* __restrict__ y1, int n){
  int node = blockIdx.x;
  if (node >= n) return;
  int f = threadIdx.x;
  float4 v = a1[node];
  float acc = v.x*W1[f] + v.y*W1[H+f] + v.z*W1[2*H+f] + b1[f];
  y1[(size_t)node*H + f] = f2bf(dinv[node] * fmaxf(acc, 0.f));
}

// prep W (K=128 x N=128, row-major fp32) into MFMA B-fragment order, bf16
__global__ __launch_bounds__(256) void k_wprep(const float* __restrict__ W, ushort16* __restrict__ wp){
  int tid = blockIdx.x*256 + threadIdx.x;   // 2048 threads total
  int frag = tid >> 6, lane = tid & 63;
  int kt = frag >> 3, ct = frag & 7;
  int m = lane & 15, quad = lane >> 4;
  const float* wrow = &W[(kt*32 + quad*8)*H + ct*16 + m];
  ushort16 vals[8];
  #pragma unroll
  for (int j = 0; j < 8; j++) vals[j] = f2bf(wrow[j*H]);
  uint4 o;
  o.x = (uint32)vals[0] | ((uint32)vals[1] << 16);
  o.y = (uint32)vals[2] | ((uint32)vals[3] << 16);
  o.z = (uint32)vals[4] | ((uint32)vals[5] << 16);
  o.w = (uint32)vals[6] | ((uint32)vals[7] << 16);
  *(uint4*)&wp[(size_t)tid*8] = o;
}

// Fused layer: a[node,:] = dinv*sum_src y[src,:] (bf16, staged in LDS), then
// out = relu(a @ W + b) via MFMA. BF16OUT: yout = bf16(dinv*out), else xout (fp32).
// 64 nodes/block, 256 threads. Aggregation: 4 passes x (16 nodes x 16 lanes x 8 feat).
template<int BF16OUT>
__global__ __launch_bounds__(256) void k_layer(const ushort16* __restrict__ y, const int* __restrict__ offsets,
      const int* __restrict__ csr_src, const float* __restrict__ dinv, const ushort16* __restrict__ wp,
      const float* __restrict__ bias,
      float* __restrict__ xout, ushort16* __restrict__ yout, int n){
  __shared__ ushort16 As[64*LSTRIDE];   // 17408 B, bf16 rows
  int tid = threadIdx.x;
  int row0 = blockIdx.x*64;

  // ---- phase A: aggregate 64 node rows into LDS ----
  #define ADDU(u) { a0+=bflo(u.x); a1+=bfhi(u.x); a2+=bflo(u.y); a3+=bfhi(u.y); \
                    a4+=bflo(u.z); a5+=bfhi(u.z); a6+=bflo(u.w); a7+=bfhi(u.w); }
  for (int pass = 0; pass < 4; pass++){
    int nl = pass*16 + (tid >> 4);     // local node 0..63
    int node = row0 + nl;
    int f8 = (tid & 15) * 8;
    float a0=0,a1=0,a2=0,a3=0,a4=0,a5=0,a6=0,a7=0;
    float dn = 0.f;
    if (node < n){
      int lo = offsets[node], hi = offsets[node+1];
      int e = lo;
      for (; e+8 <= hi; e += 8){
        int s0=csr_src[e],   s1=csr_src[e+1], s2=csr_src[e+2], s3=csr_src[e+3];
        int s4=csr_src[e+4], s5=csr_src[e+5], s6=csr_src[e+6], s7=csr_src[e+7];
        uint4 u0 = *(const uint4*)&y[(size_t)s0*H + f8];
        uint4 u1 = *(const uint4*)&y[(size_t)s1*H + f8];
        uint4 u2 = *(const uint4*)&y[(size_t)s2*H + f8];
        uint4 u3 = *(const uint4*)&y[(size_t)s3*H + f8];
        uint4 u4 = *(const uint4*)&y[(size_t)s4*H + f8];
        uint4 u5 = *(const uint4*)&y[(size_t)s5*H + f8];
        uint4 u6 = *(const uint4*)&y[(size_t)s6*H + f8];
        uint4 u7 = *(const uint4*)&y[(size_t)s7*H + f8];
        ADDU(u0); ADDU(u1); ADDU(u2); ADDU(u3);
        ADDU(u4); ADDU(u5); ADDU(u6); ADDU(u7);
      }
      for (; e < hi; e++){
        int s = csr_src[e];
        uint4 u = *(const uint4*)&y[(size_t)s*H + f8];
        ADDU(u);
      }
      dn = dinv[node];
    }
    uint4 o;
    o.x = (uint32)f2bf(a0*dn) | ((uint32)f2bf(a1*dn) << 16);
    o.y = (uint32)f2bf(a2*dn) | ((uint32)f2bf(a3*dn) << 16);
    o.z = (uint32)f2bf(a4*dn) | ((uint32)f2bf(a5*dn) << 16);
    o.w = (uint32)f2bf(a6*dn) | ((uint32)f2bf(a7*dn) << 16);
    *(uint4*)&As[nl*LSTRIDE + f8] = o;
  }
  #undef ADDU
  __syncthreads();

  // ---- phase B: MFMA dense from LDS A ----
  int wave = tid >> 6;
  int lane = tid & 63;
  int m = lane & 15, quad = lane >> 4;
  int rowb = row0 + wave*16;
  f32x4 acc[8];
  #pragma unroll
  for (int ct = 0; ct < 8; ct++){ f32x4 z = {0.f,0.f,0.f,0.f}; acc[ct] = z; }
  #pragma unroll
  for (int kt = 0; kt < 4; kt++){
    bf16x8 af = *(const bf16x8*)&As[(wave*16 + m)*LSTRIDE + kt*32 + quad*8];
    #pragma unroll
    for (int ct = 0; ct < 8; ct++){
      bf16x8 bf = *(const bf16x8*)&wp[(size_t)((kt*8+ct)*64 + lane)*8];
      acc[ct] = __builtin_amdgcn_mfma_f32_16x16x32_bf16(af, bf, acc[ct], 0, 0, 0);
    }
  }
  // C/D layout: col = ct*16 + m, row (in tile) = quad*4 + r
  #pragma unroll
  for (int ct = 0; ct < 8; ct++){
    int col = ct*16 + m;
    float bv = bias[col];
    #pragma unroll
    for (int r = 0; r < 4; r++){
      int orow = rowb + quad*4 + r;
      if (orow < n){
        float v = fmaxf(acc[ct][r] + bv, 0.f);
        if (BF16OUT) yout[(size_t)orow*H + col] = f2bf(v * dinv[orow]);
        else         xout[(size_t)orow*H + col] = v;
      }
    }
  }
}

// graph boundaries
__global__ __launch_bounds__(64) void k_bounds(const int* __restrict__ batch, int n, int G,
                                               int* __restrict__ gb){
  int g = blockIdx.x*blockDim.x + threadIdx.x;
  if (g > G) return;
  int lo = 0, hi = n;
  while (lo < hi){ int m = (lo + hi) >> 1; if (batch[m] < g) lo = m + 1; else hi = m; }
  gb[g] = lo;
}

// partial pooled sums
__global__ __launch_bounds__(128) void k_pool_partial(const float* __restrict__ x, const int* __restrict__ gb,
                                                      int S, float* __restrict__ gsum){
  int g = blockIdx.x, s = blockIdx.y;
  int lo = gb[g], hi = gb[g+1];
  int cnt = hi - lo;
  int a = lo + (int)(((long long)cnt * s) / S);
  int b = lo + (int)(((long long)cnt * (s+1)) / S);
  int f = threadIdx.x;
  float acc = 0.f;
  for (int i = a; i < b; i++) acc += x[(size_t)i*H + f];
  if (b > a) atomicAdd(&gsum[g*H + f], acc);
}

// MLP head
__global__ __launch_bounds__(64) void k_head(const float* __restrict__ gsum, const int* __restrict__ gb,
            const float* __restrict__ Wl1, const float* __restrict__ bl1,
            const float* __restrict__ Wl2, const float* __restrict__ bl2,
            float* __restrict__ out){
  int g = blockIdx.x;
  int t = threadIdx.x;
  __shared__ float gs[H];
  __shared__ float h1[64];
  float inv = 1.f / fmaxf((float)(gb[g+1] - gb[g]), 1.f);
  gs[t]      = gsum[g*H + t]      * inv;
  gs[64 + t] = gsum[g*H + 64 + t] * inv;
  __syncthreads();
  float acc = bl1[t];
  for (int k = 0; k < H; k++) acc += gs[k] * Wl1[k*64 + t];
  h1[t] = fmaxf(acc, 0.f);
  __syncthreads();
  if (t < 10){
    float o = bl2[t];
    for (int j = 0; j < 64; j++) o += h1[j] * Wl2[j*10 + t];
    out[g*10 + t] = o;
  }
}

extern "C" void kernel_launch(void* const* d_in, const int* in_sizes, int n_in,
                              void* d_out, int out_size, void* d_ws, size_t ws_size,
                              hipStream_t stream){
  const float* pos = (const float*)d_in[0];
  const int*  ei   = (const int*)d_in[1];
  const int*  batch= (const int*)d_in[2];
  const float* W1 = (const float*)d_in[3];
  const float* b1 = (const float*)d_in[4];
  const float* W2 = (const float*)d_in[5];
  const float* b2 = (const float*)d_in[6];
  const float* W3 = (const float*)d_in[7];
  const float* b3 = (const float*)d_in[8];
  const float* Wl1 = (const float*)d_in[9];
  const float* bl1 = (const float*)d_in[10];
  const float* Wl2 = (const float*)d_in[11];
  const float* bl2 = (const float*)d_in[12];
  float* out = (float*)d_out;

  int N = in_sizes[0] / 3;     // 50000
  int E = in_sizes[1] / 2;     // 800000
  int G = out_size / 10;       // 64
  const int S = 40;
  int B = (N + 1023) / 1024;   // <= 256

  // workspace carve (~40 MB; x3/ybuf double-buffer aliased over early-phase scratch)
  char* p = (char*)d_ws;
  auto carve = [&](size_t bytes)->char* { char* q = p; p += (bytes + 255) & ~(size_t)255; return q; };
  int*      deg     = (int*)     carve(sizeof(int)    * (size_t)N);
  int*      offsets = (int*)     carve(sizeof(int)    * (size_t)(N+1));
  float*    dinv    = (float*)   carve(sizeof(float)  * (size_t)N);
  int*      bsum    = (int*)     carve(sizeof(int)    * 256);
  int*      gb      = (int*)     carve(sizeof(int)    * (size_t)(G+1));
  float*    gsum    = (float*)   carve(sizeof(float)  * (size_t)G * H);
  int*      csr_src = (int*)     carve(sizeof(int)    * (size_t)(E+N));
  ushort16* ybufB   = (ushort16*)carve(sizeof(ushort16) * (size_t)N * H);  // layer-2 output y
  ushort16* wp2     = (ushort16*)carve(sizeof(ushort16) * 16384);
  ushort16* wp3     = (ushort16*)carve(sizeof(ushort16) * 16384);
  // aliased region: early {rank, y0, a1, ybufA}; late {x3}
  size_t rank_b = (sizeof(int)    * (size_t)E        + 255) & ~(size_t)255;
  size_t y0_b   = (sizeof(float4) * (size_t)N        + 255) & ~(size_t)255;
  size_t a1_b   = (sizeof(float4) * (size_t)N        + 255) & ~(size_t)255;
  size_t ybuf_b = (sizeof(ushort16)* (size_t)N * H   + 255) & ~(size_t)255;
  size_t x3_b   = (sizeof(float)  * (size_t)N * H    + 255) & ~(size_t)255;
  size_t big_b  = rank_b + y0_b + a1_b + ybuf_b;
  if (x3_b > big_b) big_b = x3_b;
  char* big = carve(big_b);
  int*      rank  = (int*)big;
  float4*   y0    = (float4*)(big + rank_b);
  float4*   a1    = (float4*)(big + rank_b + y0_b);
  ushort16* ybufA = (ushort16*)(big + rank_b + y0_b + a1_b);  // layer-1 output y
  float*    x3    = (float*)big;   // written only after last ybufA read (layer-2 k_layer)

  const int* src = ei;
  const int* dst = ei + E;

  hipMemsetAsync(deg, 0, sizeof(int)*(size_t)N, stream);
  hipMemsetAsync(gsum, 0, sizeof(float)*(size_t)G*H, stream);
  hipLaunchKernelGGL(k_bounds, dim3((G+64)/64), dim3(64), 0, stream, batch, N, G, gb);

  hipLaunchKernelGGL(k_count_rank, dim3((E+255)/256),   dim3(256), 0, stream, dst, E, deg, rank);
  hipLaunchKernelGGL(k_scan1,      dim3(B),             dim3(256), 0, stream, deg, N, offsets, bsum, dinv);
  hipLaunchKernelGGL(k_scan2,      dim3(1),             dim3(256), 0, stream, bsum, B, N, offsets);
  hipLaunchKernelGGL(k_scan3,      dim3(B),             dim3(256), 0, stream, offsets, N, bsum);
  hipLaunchKernelGGL(k_fill2,      dim3((E+N+255)/256), dim3(256), 0, stream, src, dst, E, N, offsets, rank, csr_src);

  hipLaunchKernelGGL(k_wprep, dim3(8), dim3(256), 0, stream, W2, wp2);
  hipLaunchKernelGGL(k_wprep, dim3(8), dim3(256), 0, stream, W3, wp3);

  // layer 1 (aggregate-first: tiny 3-wide gather)
  hipLaunchKernelGGL(k_prescale, dim3((N+255)/256), dim3(256), 0, stream, pos, dinv, y0, N);
  hipLaunchKernelGGL(k_agg3,     dim3((N+255)/256), dim3(256), 0, stream, y0, offsets, csr_src, dinv, a1, N);
  hipLaunchKernelGGL(k_dense1,   dim3(N),           dim3(128), 0, stream, a1, W1, b1, dinv, ybufA, N);

  // layer 2 (fused aggregate + MFMA dense), writes prescaled bf16 y into ybufB
  hipLaunchKernelGGL(k_layer<1>, dim3((N+63)/64), dim3(256), 0, stream,
                     ybufA, offsets, csr_src, dinv, wp2, b2, (float*)nullptr, ybufB, N);

  // layer 3 (fused), writes fp32 x3 (aliases ybufA region — only read ybufB here)
  hipLaunchKernelGGL(k_layer<0>, dim3((N+63)/64), dim3(256), 0, stream,
                     ybufB, offsets, csr_src, dinv, wp3, b3, x3, (ushort16*)nullptr, N);

  hipLaunchKernelGGL(k_pool_partial, dim3(G, S), dim3(128), 0, stream, x3, gb, S, gsum);
  hipLaunchKernelGGL(k_head,         dim3(G),    dim3(64),  0, stream, gsum, gb, Wl1, bl1, Wl2, bl2, out);
}

// Round 8
// 289.246 us; speedup vs baseline: 1.1365x; 1.1365x over previous
//
#include <hip/hip_runtime.h>

#define H 128
typedef unsigned int uint32;
typedef unsigned short ushort16;
typedef __attribute__((ext_vector_type(8))) short bf16x8;
typedef __attribute__((ext_vector_type(4))) float f32x4;

static __device__ __forceinline__ ushort16 f2bf(float f){
  uint32 u = __float_as_uint(f);
  uint32 r = (u + 0x7fff + ((u >> 16) & 1)) >> 16;   // RNE bf16 (finite values)
  return (ushort16)r;
}
static __device__ __forceinline__ float bflo(uint32 u){ return __uint_as_float(u << 16); }
static __device__ __forceinline__ float bfhi(uint32 u){ return __uint_as_float(u & 0xffff0000u); }

// fused setup: deg=0, gsum=0, graph boundaries gb[0..G]
__global__ __launch_bounds__(256) void k_setup(int* __restrict__ deg, float* __restrict__ gsum,
                                               const int* __restrict__ batch, int n, int G,
                                               int* __restrict__ gb){
  int i = blockIdx.x*256 + threadIdx.x;
  if (i < n) deg[i] = 0;
  if (i < G*H) gsum[i] = 0.f;
  if (i <= G){
    int lo = 0, hi = n;
    while (lo < hi){ int m = (lo + hi) >> 1; if (batch[m] < i) lo = m + 1; else hi = m; }
    gb[i] = lo;
  }
}

// rank[e] = position of edge e within its dst bucket; deg counts real in-edges
__global__ __launch_bounds__(256) void k_count_rank(const int* __restrict__ dst, int E,
                                                    int* __restrict__ deg, int* __restrict__ rank){
  int i = blockIdx.x*256 + threadIdx.x;
  if (i < E) rank[i] = atomicAdd(&deg[dst[i]], 1);
}

// ---- multi-block exclusive scan of (deg+1) -> offsets, plus dinv = rsqrt(deg+1) ----
__global__ __launch_bounds__(256) void k_scan1(const int* __restrict__ deg, int n,
      int* __restrict__ offsets, int* __restrict__ bsum, float* __restrict__ dinv){
  __shared__ int sh[256];
  int b = blockIdx.x, t = threadIdx.x;
  int base = b*1024 + t*4;
  bool i0 = base+0 < n, i1 = base+1 < n, i2 = base+2 < n, i3 = base+3 < n;
  int d0=0,d1=0,d2=0,d3=0;
  if (i3){ int4 v = *(const int4*)&deg[base]; d0=v.x; d1=v.y; d2=v.z; d3=v.w; }
  else {
    if (i0) d0 = deg[base+0];
    if (i1) d1 = deg[base+1];
    if (i2) d2 = deg[base+2];
  }
  int e0 = i0? d0+1:0, e1 = i1? d1+1:0, e2 = i2? d2+1:0, e3 = i3? d3+1:0;   // +1 self-loop
  sh[t] = e0+e1+e2+e3;
  __syncthreads();
  for (int off=1; off<256; off<<=1){
    int v = sh[t];
    int add = (t>=off)? sh[t-off] : 0;
    __syncthreads();
    sh[t] = v+add;
    __syncthreads();
  }
  int o0 = (t==0)?0:sh[t-1];
  int o1 = o0+e0, o2 = o1+e1, o3 = o2+e2;
  if (i0){ offsets[base+0]=o0; dinv[base+0]=rsqrtf((float)(d0+1)); }
  if (i1){ offsets[base+1]=o1; dinv[base+1]=rsqrtf((float)(d1+1)); }
  if (i2){ offsets[base+2]=o2; dinv[base+2]=rsqrtf((float)(d2+1)); }
  if (i3){ offsets[base+3]=o3; dinv[base+3]=rsqrtf((float)(d3+1)); }
  if (t==255) bsum[b] = sh[255];
}

__global__ __launch_bounds__(256) void k_scan2(int* __restrict__ bsum, int B, int n, int* __restrict__ offsets){
  __shared__ int sh[256];
  int t = threadIdx.x;
  sh[t] = (t<B)? bsum[t] : 0;
  __syncthreads();
  for (int off=1; off<256; off<<=1){
    int v = sh[t];
    int add = (t>=off)? sh[t-off] : 0;
    __syncthreads();
    sh[t] = v+add;
    __syncthreads();
  }
  if (t<B) bsum[t] = (t==0)?0:sh[t-1];
  if (t==255) offsets[n] = sh[255];
}

__global__ __launch_bounds__(256) void k_scan3(int* __restrict__ offsets, int n, const int* __restrict__ bsum){
  int b = blockIdx.x, t = threadIdx.x;
  int add = bsum[b];
  int base = b*1024 + t*4;
  if (base+3 < n){
    int4 v = *(int4*)&offsets[base];
    v.x+=add; v.y+=add; v.z+=add; v.w+=add;
    *(int4*)&offsets[base] = v;
  } else {
    #pragma unroll
    for (int k=0;k<4;k++){ int i=base+k; if (i<n) offsets[i]+=add; }
  }
}

// atomic-free CSR fill: real edge e -> slot offsets[dst]+1+rank[e]; self-loop at slot offsets[i]
__global__ __launch_bounds__(256) void k_fill2(const int* __restrict__ src, const int* __restrict__ dst,
            int E, int n, const int* __restrict__ offsets, const int* __restrict__ rank,
            int* __restrict__ csr_src){
  int i = blockIdx.x*256 + threadIdx.x;
  if (i < E){
    csr_src[offsets[dst[i]] + 1 + rank[i]] = src[i];
  } else if (i < E + n){
    int j = i - E;
    csr_src[offsets[j]] = j;
  }
}

// y0[i] = dinv[i] * pos[i]  (padded float4)
__global__ __launch_bounds__(256) void k_prescale(const float* __restrict__ pos, const float* __restrict__ dinv,
                                                  float4* __restrict__ y0, int n){
  int i = blockIdx.x*256 + threadIdx.x;
  if (i < n){
    float d = dinv[i];
    y0[i] = make_float4(pos[3*i]*d, pos[3*i+1]*d, pos[3*i+2]*d, 0.f);
  }
}

// a1[d] = dinv[d] * sum_src y0[src]
__global__ __launch_bounds__(256) void k_agg3(const float4* __restrict__ y0, const int* __restrict__ offsets,
      const int* __restrict__ csr_src, const float* __restrict__ dinv, float4* __restrict__ a1, int n){
  int node = blockIdx.x*256 + threadIdx.x;
  if (node >= n) return;
  int lo = offsets[node], hi = offsets[node+1];
  float x=0.f, y=0.f, z=0.f;
  int e = lo;
  for (; e+2 <= hi; e += 2){
    int s0 = csr_src[e], s1 = csr_src[e+1];
    float4 v0 = y0[s0], v1 = y0[s1];
    x += v0.x + v1.x; y += v0.y + v1.y; z += v0.z + v1.z;
  }
  if (e < hi){ float4 v = y0[csr_src[e]]; x += v.x; y += v.y; z += v.z; }
  float dn = dinv[node];
  a1[node] = make_float4(x*dn, y*dn, z*dn, 0.f);
}

// y1[node,f] = bf16( dinv[node] * relu(a1[node] . W1[:,f] + b1[f]) )
__global__ __launch_bounds__(128) void k_dense1(const float4* __restrict__ a1, const float* __restrict__ W1,
      const float* __restrict__ b1, const float* __restrict__ dinv, ushort16* __restrict__ y1, int n){
  int node = blockIdx.x;
  if (node >= n) return;
  int f = threadIdx.x;
  float4 v = a1[node];
  float acc = v.x*W1[f] + v.y*W1[H+f] + v.z*W1[2*H+f] + b1[f];
  y1[(size_t)node*H + f] = f2bf(dinv[node] * fmaxf(acc, 0.f));
}

// a[d,:] = bf16( dinv[d] * sum_src y[src,:] )   (bf16 gather, fp32 accumulate, bf16 out)
// 16 nodes per 256-thread block; 16 lanes per node, 16B (8 bf16) per lane; unroll-8
__global__ __launch_bounds__(256) void k_agg128(const ushort16* __restrict__ y, const int* __restrict__ offsets,
      const int* __restrict__ csr_src, const float* __restrict__ dinv, ushort16* __restrict__ aout, int n){
  int node = blockIdx.x*16 + (threadIdx.x >> 4);
  if (node >= n) return;
  int f8 = (threadIdx.x & 15) * 8;
  int lo = offsets[node], hi = offsets[node+1];
  float a0=0,a1=0,a2=0,a3=0,a4=0,a5=0,a6=0,a7=0;
  #define ADDU(u) { a0+=bflo(u.x); a1+=bfhi(u.x); a2+=bflo(u.y); a3+=bfhi(u.y); \
                    a4+=bflo(u.z); a5+=bfhi(u.z); a6+=bflo(u.w); a7+=bfhi(u.w); }
  int e = lo;
  for (; e+8 <= hi; e += 8){
    int s0=csr_src[e],   s1=csr_src[e+1], s2=csr_src[e+2], s3=csr_src[e+3];
    int s4=csr_src[e+4], s5=csr_src[e+5], s6=csr_src[e+6], s7=csr_src[e+7];
    uint4 u0 = *(const uint4*)&y[(size_t)s0*H + f8];
    uint4 u1 = *(const uint4*)&y[(size_t)s1*H + f8];
    uint4 u2 = *(const uint4*)&y[(size_t)s2*H + f8];
    uint4 u3 = *(const uint4*)&y[(size_t)s3*H + f8];
    uint4 u4 = *(const uint4*)&y[(size_t)s4*H + f8];
    uint4 u5 = *(const uint4*)&y[(size_t)s5*H + f8];
    uint4 u6 = *(const uint4*)&y[(size_t)s6*H + f8];
    uint4 u7 = *(const uint4*)&y[(size_t)s7*H + f8];
    ADDU(u0); ADDU(u1); ADDU(u2); ADDU(u3);
    ADDU(u4); ADDU(u5); ADDU(u6); ADDU(u7);
  }
  for (; e < hi; e++){
    int s = csr_src[e];
    uint4 u = *(const uint4*)&y[(size_t)s*H + f8];
    ADDU(u);
  }
  #undef ADDU
  float dn = dinv[node];
  uint4 o;
  o.x = (uint32)f2bf(a0*dn) | ((uint32)f2bf(a1*dn) << 16);
  o.y = (uint32)f2bf(a2*dn) | ((uint32)f2bf(a3*dn) << 16);
  o.z = (uint32)f2bf(a4*dn) | ((uint32)f2bf(a5*dn) << 16);
  o.w = (uint32)f2bf(a6*dn) | ((uint32)f2bf(a7*dn) << 16);
  *(uint4*)&aout[(size_t)node*H + f8] = o;
}

// prep W (K=128 x N=128, row-major fp32) into MFMA B-fragment order, bf16
__global__ __launch_bounds__(256) void k_wprep(const float* __restrict__ W, ushort16* __restrict__ wp){
  int tid = blockIdx.x*256 + threadIdx.x;   // 2048 threads total
  int frag = tid >> 6, lane = tid & 63;
  int kt = frag >> 3, ct = frag & 7;
  int m = lane & 15, quad = lane >> 4;
  const float* wrow = &W[(kt*32 + quad*8)*H + ct*16 + m];
  ushort16 vals[8];
  #pragma unroll
  for (int j = 0; j < 8; j++) vals[j] = f2bf(wrow[j*H]);
  uint4 o;
  o.x = (uint32)vals[0] | ((uint32)vals[1] << 16);
  o.y = (uint32)vals[2] | ((uint32)vals[3] << 16);
  o.z = (uint32)vals[4] | ((uint32)vals[5] << 16);
  o.w = (uint32)vals[6] | ((uint32)vals[7] << 16);
  *(uint4*)&wp[(size_t)tid*8] = o;
}

// MFMA dense: out = relu(a @ W + b); BF16OUT: y = bf16(dinv*out), else x = out (fp32)
// 64 rows/block, 4 waves x 16 rows, K=128 in 4 steps, 8 col-tiles of 16. No LDS.
template<int BF16OUT>
__global__ __launch_bounds__(256) void k_dense_mfma(const ushort16* __restrict__ a, const ushort16* __restrict__ wp,
      const float* __restrict__ bias, const float* __restrict__ dinv,
      float* __restrict__ xout, ushort16* __restrict__ yout, int n){
  int wave = threadIdx.x >> 6;
  int lane = threadIdx.x & 63;
  int m = lane & 15, quad = lane >> 4;
  int row0 = blockIdx.x*64 + wave*16;
  int arow = row0 + m;                 // A-operand row for this lane
  bool aok = arow < n;
  const bf16x8 az = {0,0,0,0,0,0,0,0};
  f32x4 acc[8];
  #pragma unroll
  for (int ct = 0; ct < 8; ct++){ f32x4 z = {0.f,0.f,0.f,0.f}; acc[ct] = z; }
  #pragma unroll
  for (int kt = 0; kt < 4; kt++){
    bf16x8 af = aok ? *(const bf16x8*)&a[(size_t)arow*H + kt*32 + quad*8] : az;
    #pragma unroll
    for (int ct = 0; ct < 8; ct++){
      bf16x8 bf = *(const bf16x8*)&wp[(size_t)((kt*8+ct)*64 + lane)*8];
      acc[ct] = __builtin_amdgcn_mfma_f32_16x16x32_bf16(af, bf, acc[ct], 0, 0, 0);
    }
  }
  // C/D layout: col = ct*16 + m, row (in tile) = quad*4 + r
  #pragma unroll
  for (int ct = 0; ct < 8; ct++){
    int col = ct*16 + m;
    float bv = bias[col];
    #pragma unroll
    for (int r = 0; r < 4; r++){
      int orow = row0 + quad*4 + r;
      if (orow < n){
        float v = fmaxf(acc[ct][r] + bv, 0.f);
        if (BF16OUT) yout[(size_t)orow*H + col] = f2bf(v * dinv[orow]);
        else         xout[(size_t)orow*H + col] = v;
      }
    }
  }
}

// partial pooled sums
__global__ __launch_bounds__(128) void k_pool_partial(const float* __restrict__ x, const int* __restrict__ gb,
                                                      int S, float* __restrict__ gsum){
  int g = blockIdx.x, s = blockIdx.y;
  int lo = gb[g], hi = gb[g+1];
  int cnt = hi - lo;
  int a = lo + (int)(((long long)cnt * s) / S);
  int b = lo + (int)(((long long)cnt * (s+1)) / S);
  int f = threadIdx.x;
  float acc = 0.f;
  for (int i = a; i < b; i++) acc += x[(size_t)i*H + f];
  if (b > a) atomicAdd(&gsum[g*H + f], acc);
}

// MLP head
__global__ __launch_bounds__(64) void k_head(const float* __restrict__ gsum, const int* __restrict__ gb,
            const float* __restrict__ Wl1, const float* __restrict__ bl1,
            const float* __restrict__ Wl2, const float* __restrict__ bl2,
            float* __restrict__ out){
  int g = blockIdx.x;
  int t = threadIdx.x;
  __shared__ float gs[H];
  __shared__ float h1[64];
  float inv = 1.f / fmaxf((float)(gb[g+1] - gb[g]), 1.f);
  gs[t]      = gsum[g*H + t]      * inv;
  gs[64 + t] = gsum[g*H + 64 + t] * inv;
  __syncthreads();
  float acc = bl1[t];
  for (int k = 0; k < H; k++) acc += gs[k] * Wl1[k*64 + t];
  h1[t] = fmaxf(acc, 0.f);
  __syncthreads();
  if (t < 10){
    float o = bl2[t];
    for (int j = 0; j < 64; j++) o += h1[j] * Wl2[j*10 + t];
    out[g*10 + t] = o;
  }
}

extern "C" void kernel_launch(void* const* d_in, const int* in_sizes, int n_in,
                              void* d_out, int out_size, void* d_ws, size_t ws_size,
                              hipStream_t stream){
  const float* pos = (const float*)d_in[0];
  const int*  ei   = (const int*)d_in[1];
  const int*  batch= (const int*)d_in[2];
  const float* W1 = (const float*)d_in[3];
  const float* b1 = (const float*)d_in[4];
  const float* W2 = (const float*)d_in[5];
  const float* b2 = (const float*)d_in[6];
  const float* W3 = (const float*)d_in[7];
  const float* b3 = (const float*)d_in[8];
  const float* Wl1 = (const float*)d_in[9];
  const float* bl1 = (const float*)d_in[10];
  const float* Wl2 = (const float*)d_in[11];
  const float* bl2 = (const float*)d_in[12];
  float* out = (float*)d_out;

  int N = in_sizes[0] / 3;     // 50000
  int E = in_sizes[1] / 2;     // 800000
  int G = out_size / 10;       // 64
  const int S = 40;
  int B = (N + 1023) / 1024;   // <= 256

  // workspace carve (~43 MB; x3 aliases the dead rank/y0/a1/ybuf region)
  char* p = (char*)d_ws;
  auto carve = [&](size_t bytes)->char* { char* q = p; p += (bytes + 255) & ~(size_t)255; return q; };
  int*      deg     = (int*)     carve(sizeof(int)    * (size_t)N);
  int*      offsets = (int*)     carve(sizeof(int)    * (size_t)(N+1));
  float*    dinv    = (float*)   carve(sizeof(float)  * (size_t)N);
  int*      bsum    = (int*)     carve(sizeof(int)    * 256);
  int*      gb      = (int*)     carve(sizeof(int)    * (size_t)(G+1));
  float*    gsum    = (float*)   carve(sizeof(float)  * (size_t)G * H);
  int*      csr_src = (int*)     carve(sizeof(int)    * (size_t)(E+N));
  ushort16* abuf    = (ushort16*)carve(sizeof(ushort16) * (size_t)N * H);   // a2/a3 bf16
  ushort16* wp2     = (ushort16*)carve(sizeof(ushort16) * 16384);
  ushort16* wp3     = (ushort16*)carve(sizeof(ushort16) * 16384);
  // big aliased region: early phase {rank, y0, a1, ybuf}; late phase {x3}
  size_t rank_b = (sizeof(int)    * (size_t)E        + 255) & ~(size_t)255;
  size_t y0_b   = (sizeof(float4) * (size_t)N        + 255) & ~(size_t)255;
  size_t a1_b   = (sizeof(float4) * (size_t)N        + 255) & ~(size_t)255;
  size_t ybuf_b = (sizeof(ushort16)* (size_t)N * H   + 255) & ~(size_t)255;
  size_t x3_b   = (sizeof(float)  * (size_t)N * H    + 255) & ~(size_t)255;
  size_t big_b  = rank_b + y0_b + a1_b + ybuf_b;
  if (x3_b > big_b) big_b = x3_b;
  char* big = carve(big_b);
  int*      rank = (int*)big;
  float4*   y0   = (float4*)(big + rank_b);
  float4*   a1   = (float4*)(big + rank_b + y0_b);
  ushort16* ybuf = (ushort16*)(big + rank_b + y0_b + a1_b);
  float*    x3   = (float*)big;   // written only after last ybuf read

  const int* src = ei;
  const int* dst = ei + E;

  hipLaunchKernelGGL(k_setup, dim3((N+255)/256), dim3(256), 0, stream, deg, gsum, batch, N, G, gb);

  hipLaunchKernelGGL(k_count_rank, dim3((E+255)/256),   dim3(256), 0, stream, dst, E, deg, rank);
  hipLaunchKernelGGL(k_scan1,      dim3(B),             dim3(256), 0, stream, deg, N, offsets, bsum, dinv);
  hipLaunchKernelGGL(k_scan2,      dim3(1),             dim3(256), 0, stream, bsum, B, N, offsets);
  hipLaunchKernelGGL(k_scan3,      dim3(B),             dim3(256), 0, stream, offsets, N, bsum);
  hipLaunchKernelGGL(k_fill2,      dim3((E+N+255)/256), dim3(256), 0, stream, src, dst, E, N, offsets, rank, csr_src);

  hipLaunchKernelGGL(k_wprep, dim3(8), dim3(256), 0, stream, W2, wp2);
  hipLaunchKernelGGL(k_wprep, dim3(8), dim3(256), 0, stream, W3, wp3);

  // layer 1 (aggregate-first: tiny 3-wide gather)
  hipLaunchKernelGGL(k_prescale, dim3((N+255)/256), dim3(256), 0, stream, pos, dinv, y0, N);
  hipLaunchKernelGGL(k_agg3,     dim3((N+255)/256), dim3(256), 0, stream, y0, offsets, csr_src, dinv, a1, N);
  hipLaunchKernelGGL(k_dense1,   dim3(N),           dim3(128), 0, stream, a1, W1, b1, dinv, ybuf, N);

  // layer 2
  hipLaunchKernelGGL(k_agg128,        dim3((N+15)/16), dim3(256), 0, stream, ybuf, offsets, csr_src, dinv, abuf, N);
  hipLaunchKernelGGL(k_dense_mfma<1>, dim3((N+63)/64), dim3(256), 0, stream, abuf, wp2, b2, dinv, (float*)nullptr, ybuf, N);

  // layer 3
  hipLaunchKernelGGL(k_agg128,        dim3((N+15)/16), dim3(256), 0, stream, ybuf, offsets, csr_src, dinv, abuf, N);
  hipLaunchKernelGGL(k_dense_mfma<0>, dim3((N+63)/64), dim3(256), 0, stream, abuf, wp3, b3, dinv, x3, (ushort16*)nullptr, N);

  hipLaunchKernelGGL(k_pool_partial, dim3(G, S), dim3(128), 0, stream, x3, gb, S, gsum);
  hipLaunchKernelGGL(k_head,         dim3(G),    dim3(64),  0, stream, gsum, gb, Wl1, bl1, Wl2, bl2, out);
}

// Round 9
// 269.116 us; speedup vs baseline: 1.2215x; 1.0748x over previous
//
#include <hip/hip_runtime.h>

#define H 128
#define LSTRIDE 136   // LDS row stride in bf16 elems: 272B, 16B-aligned, 2-way bank (free)
typedef unsigned int uint32;
typedef unsigned short ushort16;
typedef __attribute__((ext_vector_type(8))) short bf16x8;
typedef __attribute__((ext_vector_type(4))) float f32x4;

static __device__ __forceinline__ ushort16 f2bf(float f){
  uint32 u = __float_as_uint(f);
  uint32 r = (u + 0x7fff + ((u >> 16) & 1)) >> 16;   // RNE bf16 (finite values)
  return (ushort16)r;
}
static __device__ __forceinline__ float bflo(uint32 u){ return __uint_as_float(u << 16); }
static __device__ __forceinline__ float bfhi(uint32 u){ return __uint_as_float(u & 0xffff0000u); }

// fused setup: deg=0, gsum=0, graph boundaries gb[0..G]
__global__ __launch_bounds__(256) void k_setup(int* __restrict__ deg, float* __restrict__ gsum,
                                               const int* __restrict__ batch, int n, int G,
                                               int* __restrict__ gb){
  int i = blockIdx.x*256 + threadIdx.x;
  if (i < n) deg[i] = 0;
  if (i < G*H) gsum[i] = 0.f;
  if (i <= G){
    int lo = 0, hi = n;
    while (lo < hi){ int m = (lo + hi) >> 1; if (batch[m] < i) lo = m + 1; else hi = m; }
    gb[i] = lo;
  }
}

// rank[e] = position of edge e within its dst bucket; deg counts real in-edges
__global__ __launch_bounds__(256) void k_count_rank(const int* __restrict__ dst, int E,
                                                    int* __restrict__ deg, int* __restrict__ rank){
  int i = blockIdx.x*256 + threadIdx.x;
  if (i < E) rank[i] = atomicAdd(&deg[dst[i]], 1);
}

// ---- scan of (deg+1) -> block-local offsets, block totals to bsum, dinv ----
__global__ __launch_bounds__(256) void k_scan1(const int* __restrict__ deg, int n,
      int* __restrict__ offsets, int* __restrict__ bsum, float* __restrict__ dinv){
  __shared__ int sh[256];
  int b = blockIdx.x, t = threadIdx.x;
  int base = b*1024 + t*4;
  bool i0 = base+0 < n, i1 = base+1 < n, i2 = base+2 < n, i3 = base+3 < n;
  int d0=0,d1=0,d2=0,d3=0;
  if (i3){ int4 v = *(const int4*)&deg[base]; d0=v.x; d1=v.y; d2=v.z; d3=v.w; }
  else {
    if (i0) d0 = deg[base+0];
    if (i1) d1 = deg[base+1];
    if (i2) d2 = deg[base+2];
  }
  int e0 = i0? d0+1:0, e1 = i1? d1+1:0, e2 = i2? d2+1:0, e3 = i3? d3+1:0;   // +1 self-loop
  sh[t] = e0+e1+e2+e3;
  __syncthreads();
  for (int off=1; off<256; off<<=1){
    int v = sh[t];
    int add = (t>=off)? sh[t-off] : 0;
    __syncthreads();
    sh[t] = v+add;
    __syncthreads();
  }
  int o0 = (t==0)?0:sh[t-1];
  int o1 = o0+e0, o2 = o1+e1, o3 = o2+e2;
  if (i0){ offsets[base+0]=o0; dinv[base+0]=rsqrtf((float)(d0+1)); }
  if (i1){ offsets[base+1]=o1; dinv[base+1]=rsqrtf((float)(d1+1)); }
  if (i2){ offsets[base+2]=o2; dinv[base+2]=rsqrtf((float)(d2+1)); }
  if (i3){ offsets[base+3]=o3; dinv[base+3]=rsqrtf((float)(d3+1)); }
  if (t==255) bsum[b] = sh[255];
}

// add block prefix; prefix computed in-wave from bsum (requires B <= 64). Last block writes offsets[n].
__global__ __launch_bounds__(256) void k_scan3b(int* __restrict__ offsets, int n,
                                                const int* __restrict__ bsum, int B){
  __shared__ int sh[2];
  int b = blockIdx.x, t = threadIdx.x;
  if (t < 64){
    int v   = (t < B)? bsum[t] : 0;
    int pre = (t < b)? v : 0;
    int tot = v;
    for (int o=1; o<64; o<<=1){ pre += __shfl_xor(pre,o); tot += __shfl_xor(tot,o); }
    if (t == 0){ sh[0] = pre; sh[1] = tot; }
  }
  __syncthreads();
  int add = sh[0];
  int base = b*1024 + t*4;
  if (base+3 < n){
    int4 v = *(int4*)&offsets[base];
    v.x+=add; v.y+=add; v.z+=add; v.w+=add;
    *(int4*)&offsets[base] = v;
  } else {
    #pragma unroll
    for (int k=0;k<4;k++){ int i=base+k; if (i<n) offsets[i]+=add; }
  }
  if (b == B-1 && t == 255) offsets[n] = sh[1];
}

// atomic-free CSR fill: real edge e -> slot offsets[dst]+1+rank[e]; self-loop at slot offsets[i]
__global__ __launch_bounds__(256) void k_fill2(const int* __restrict__ src, const int* __restrict__ dst,
            int E, int n, const int* __restrict__ offsets, const int* __restrict__ rank,
            int* __restrict__ csr_src){
  int i = blockIdx.x*256 + threadIdx.x;
  if (i < E){
    csr_src[offsets[dst[i]] + 1 + rank[i]] = src[i];
  } else if (i < E + n){
    int j = i - E;
    csr_src[offsets[j]] = j;
  }
}

// y0[i] = dinv[i] * pos[i]  (padded float4)
__global__ __launch_bounds__(256) void k_prescale(const float* __restrict__ pos, const float* __restrict__ dinv,
                                                  float4* __restrict__ y0, int n){
  int i = blockIdx.x*256 + threadIdx.x;
  if (i < n){
    float d = dinv[i];
    y0[i] = make_float4(pos[3*i]*d, pos[3*i+1]*d, pos[3*i+2]*d, 0.f);
  }
}

// a1[d] = dinv[d] * sum_src y0[src]
__global__ __launch_bounds__(256) void k_agg3(const float4* __restrict__ y0, const int* __restrict__ offsets,
      const int* __restrict__ csr_src, const float* __restrict__ dinv, float4* __restrict__ a1, int n){
  int node = blockIdx.x*256 + threadIdx.x;
  if (node >= n) return;
  int lo = offsets[node], hi = offsets[node+1];
  float x=0.f, y=0.f, z=0.f;
  int e = lo;
  for (; e+2 <= hi; e += 2){
    int s0 = csr_src[e], s1 = csr_src[e+1];
    float4 v0 = y0[s0], v1 = y0[s1];
    x += v0.x + v1.x; y += v0.y + v1.y; z += v0.z + v1.z;
  }
  if (e < hi){ float4 v = y0[csr_src[e]]; x += v.x; y += v.y; z += v.z; }
  float dn = dinv[node];
  a1[node] = make_float4(x*dn, y*dn, z*dn, 0.f);
}

// y1[node,f] = bf16( dinv[node] * relu(a1[node] . W1[:,f] + b1[f]) )
__global__ __launch_bounds__(128) void k_dense1(const float4* __restrict__ a1, const float* __restrict__ W1,
      const float* __restrict__ b1, const float* __restrict__ dinv, ushort16* __restrict__ y1, int n){
  int node = blockIdx.x;
  if (node >= n) return;
  int f = threadIdx.x;
  float4 v = a1[node];
  float acc = v.x*W1[f] + v.y*W1[H+f] + v.z*W1[2*H+f] + b1[f];
  y1[(size_t)node*H + f] = f2bf(dinv[node] * fmaxf(acc, 0.f));
}

// prep W2+W3 (each K=128 x N=128, row-major fp32) into MFMA B-fragment order, bf16
__global__ __launch_bounds__(256) void k_wprep2(const float* __restrict__ W2, const float* __restrict__ W3,
                                                ushort16* __restrict__ wp2, ushort16* __restrict__ wp3){
  int gid = blockIdx.x*256 + threadIdx.x;   // 4096 threads total
  const float* W = (gid < 2048) ? W2 : W3;
  ushort16* wp   = (gid < 2048) ? wp2 : wp3;
  int tid = gid & 2047;
  int frag = tid >> 6, lane = tid & 63;
  int kt = frag >> 3, ct = frag & 7;
  int m = lane & 15, quad = lane >> 4;
  const float* wrow = &W[(kt*32 + quad*8)*H + ct*16 + m];
  ushort16 vals[8];
  #pragma unroll
  for (int j = 0; j < 8; j++) vals[j] = f2bf(wrow[j*H]);
  uint4 o;
  o.x = (uint32)vals[0] | ((uint32)vals[1] << 16);
  o.y = (uint32)vals[2] | ((uint32)vals[3] << 16);
  o.z = (uint32)vals[4] | ((uint32)vals[5] << 16);
  o.w = (uint32)vals[6] | ((uint32)vals[7] << 16);
  *(uint4*)&wp[(size_t)tid*8] = o;
}

// Fused aggregate + MFMA dense, FULL gather parallelism preserved:
// 16 nodes per 256-thread block (16 lanes/node, one pass — same as standalone agg128),
// aggregated bf16 rows staged in LDS, then 4 waves x 2 col-tiles of MFMA.
// BF16OUT: yout = bf16(dinv*relu(aW+b)), else xout = relu(aW+b) fp32.
template<int BF16OUT>
__global__ __launch_bounds__(256) void k_aggdense(const ushort16* __restrict__ y, const int* __restrict__ offsets,
      const int* __restrict__ csr_src, const float* __restrict__ dinv, const ushort16* __restrict__ wp,
      const float* __restrict__ bias,
      float* __restrict__ xout, ushort16* __restrict__ yout, int n){
  __shared__ unsigned short As[16*LSTRIDE];   // 4352 B
  int tid = threadIdx.x;
  int node16 = blockIdx.x*16;
  int nl = tid >> 4;                 // local node 0..15
  int node = node16 + nl;
  int f8 = (tid & 15) * 8;

  // ---- phase A: aggregate (identical parallelism to standalone agg128) ----
  float a0=0,a1=0,a2=0,a3=0,a4=0,a5=0,a6=0,a7=0;
  float dn = 0.f;
  #define ADDU(u) { a0+=bflo(u.x); a1+=bfhi(u.x); a2+=bflo(u.y); a3+=bfhi(u.y); \
                    a4+=bflo(u.z); a5+=bfhi(u.z); a6+=bflo(u.w); a7+=bfhi(u.w); }
  if (node < n){
    int lo = offsets[node], hi = offsets[node+1];
    int e = lo;
    for (; e+8 <= hi; e += 8){
      int s0=csr_src[e],   s1=csr_src[e+1], s2=csr_src[e+2], s3=csr_src[e+3];
      int s4=csr_src[e+4], s5=csr_src[e+5], s6=csr_src[e+6], s7=csr_src[e+7];
      uint4 u0 = *(const uint4*)&y[(size_t)s0*H + f8];
      uint4 u1 = *(const uint4*)&y[(size_t)s1*H + f8];
      uint4 u2 = *(const uint4*)&y[(size_t)s2*H + f8];
      uint4 u3 = *(const uint4*)&y[(size_t)s3*H + f8];
      uint4 u4 = *(const uint4*)&y[(size_t)s4*H + f8];
      uint4 u5 = *(const uint4*)&y[(size_t)s5*H + f8];
      uint4 u6 = *(const uint4*)&y[(size_t)s6*H + f8];
      uint4 u7 = *(const uint4*)&y[(size_t)s7*H + f8];
      ADDU(u0); ADDU(u1); ADDU(u2); ADDU(u3);
      ADDU(u4); ADDU(u5); ADDU(u6); ADDU(u7);
    }
    for (; e < hi; e++){
      int s = csr_src[e];
      uint4 u = *(const uint4*)&y[(size_t)s*H + f8];
      ADDU(u);
    }
    dn = dinv[node];
  }
  #undef ADDU
  uint4 o;
  o.x = (uint32)f2bf(a0*dn) | ((uint32)f2bf(a1*dn) << 16);
  o.y = (uint32)f2bf(a2*dn) | ((uint32)f2bf(a3*dn) << 16);
  o.z = (uint32)f2bf(a4*dn) | ((uint32)f2bf(a5*dn) << 16);
  o.w = (uint32)f2bf(a6*dn) | ((uint32)f2bf(a7*dn) << 16);
  *(uint4*)&As[nl*LSTRIDE + f8] = o;
  __syncthreads();

  // ---- phase B: MFMA — wave w handles col-tiles {2w, 2w+1} over the 16 staged rows ----
  int wave = tid >> 6;
  int lane = tid & 63;
  int m = lane & 15, quad = lane >> 4;
  f32x4 acc0 = {0.f,0.f,0.f,0.f}, acc1 = {0.f,0.f,0.f,0.f};
  int ct0 = wave*2, ct1 = wave*2 + 1;
  #pragma unroll
  for (int kt = 0; kt < 4; kt++){
    bf16x8 af = *(const bf16x8*)&As[m*LSTRIDE + kt*32 + quad*8];
    bf16x8 b0 = *(const bf16x8*)&wp[(size_t)((kt*8+ct0)*64 + lane)*8];
    bf16x8 b1 = *(const bf16x8*)&wp[(size_t)((kt*8+ct1)*64 + lane)*8];
    acc0 = __builtin_amdgcn_mfma_f32_16x16x32_bf16(af, b0, acc0, 0, 0, 0);
    acc1 = __builtin_amdgcn_mfma_f32_16x16x32_bf16(af, b1, acc1, 0, 0, 0);
  }
  // C/D layout: col = ct*16 + m, row (in tile) = quad*4 + r
  #pragma unroll
  for (int j = 0; j < 2; j++){
    int ct = wave*2 + j;
    int col = ct*16 + m;
    float bv = bias[col];
    f32x4 ac = j ? acc1 : acc0;
    #pragma unroll
    for (int r = 0; r < 4; r++){
      int orow = node16 + quad*4 + r;
      if (orow < n){
        float v = fmaxf(ac[r] + bv, 0.f);
        if (BF16OUT) yout[(size_t)orow*H + col] = f2bf(v * dinv[orow]);
        else         xout[(size_t)orow*H + col] = v;
      }
    }
  }
}

// partial pooled sums
__global__ __launch_bounds__(128) void k_pool_partial(const float* __restrict__ x, const int* __restrict__ gb,
                                                      int S, float* __restrict__ gsum){
  int g = blockIdx.x, s = blockIdx.y;
  int lo = gb[g], hi = gb[g+1];
  int cnt = hi - lo;
  int a = lo + (int)(((long long)cnt * s) / S);
  int b = lo + (int)(((long long)cnt * (s+1)) / S);
  int f = threadIdx.x;
  float acc = 0.f;
  for (int i = a; i < b; i++) acc += x[(size_t)i*H + f];
  if (b > a) atomicAdd(&gsum[g*H + f], acc);
}

// MLP head
__global__ __launch_bounds__(64) void k_head(const float* __restrict__ gsum, const int* __restrict__ gb,
            const float* __restrict__ Wl1, const float* __restrict__ bl1,
            const float* __restrict__ Wl2, const float* __restrict__ bl2,
            float* __restrict__ out){
  int g = blockIdx.x;
  int t = threadIdx.x;
  __shared__ float gs[H];
  __shared__ float h1[64];
  float inv = 1.f / fmaxf((float)(gb[g+1] - gb[g]), 1.f);
  gs[t]      = gsum[g*H + t]      * inv;
  gs[64 + t] = gsum[g*H + 64 + t] * inv;
  __syncthreads();
  float acc = bl1[t];
  for (int k = 0; k < H; k++) acc += gs[k] * Wl1[k*64 + t];
  h1[t] = fmaxf(acc, 0.f);
  __syncthreads();
  if (t < 10){
    float o = bl2[t];
    for (int j = 0; j < 64; j++) o += h1[j] * Wl2[j*10 + t];
    out[g*10 + t] = o;
  }
}

extern "C" void kernel_launch(void* const* d_in, const int* in_sizes, int n_in,
                              void* d_out, int out_size, void* d_ws, size_t ws_size,
                              hipStream_t stream){
  const float* pos = (const float*)d_in[0];
  const int*  ei   = (const int*)d_in[1];
  const int*  batch= (const int*)d_in[2];
  const float* W1 = (const float*)d_in[3];
  const float* b1 = (const float*)d_in[4];
  const float* W2 = (const float*)d_in[5];
  const float* b2 = (const float*)d_in[6];
  const float* W3 = (const float*)d_in[7];
  const float* b3 = (const float*)d_in[8];
  const float* Wl1 = (const float*)d_in[9];
  const float* bl1 = (const float*)d_in[10];
  const float* Wl2 = (const float*)d_in[11];
  const float* bl2 = (const float*)d_in[12];
  float* out = (float*)d_out;

  int N = in_sizes[0] / 3;     // 50000
  int E = in_sizes[1] / 2;     // 800000
  int G = out_size / 10;       // 64
  const int S = 40;
  int B = (N + 1023) / 1024;   // 49, must be <= 64 for k_scan3b

  // workspace carve (~43 MB; x3 aliases the dead rank/y0/a1/ybufA region)
  char* p = (char*)d_ws;
  auto carve = [&](size_t bytes)->char* { char* q = p; p += (bytes + 255) & ~(size_t)255; return q; };
  int*      deg     = (int*)     carve(sizeof(int)    * (size_t)N);
  int*      offsets = (int*)     carve(sizeof(int)    * (size_t)(N+1));
  float*    dinv    = (float*)   carve(sizeof(float)  * (size_t)N);
  int*      bsum    = (int*)     carve(sizeof(int)    * 256);
  int*      gb      = (int*)     carve(sizeof(int)    * (size_t)(G+1));
  float*    gsum    = (float*)   carve(sizeof(float)  * (size_t)G * H);
  int*      csr_src = (int*)     carve(sizeof(int)    * (size_t)(E+N));
  ushort16* ybufB   = (ushort16*)carve(sizeof(ushort16) * (size_t)N * H);   // layer-2 output y
  ushort16* wp2     = (ushort16*)carve(sizeof(ushort16) * 16384);
  ushort16* wp3     = (ushort16*)carve(sizeof(ushort16) * 16384);
  // aliased region: early {rank, y0, a1, ybufA}; late {x3}
  size_t rank_b = (sizeof(int)    * (size_t)E        + 255) & ~(size_t)255;
  size_t y0_b   = (sizeof(float4) * (size_t)N        + 255) & ~(size_t)255;
  size_t a1_b   = (sizeof(float4) * (size_t)N        + 255) & ~(size_t)255;
  size_t ybuf_b = (sizeof(ushort16)* (size_t)N * H   + 255) & ~(size_t)255;
  size_t x3_b   = (sizeof(float)  * (size_t)N * H    + 255) & ~(size_t)255;
  size_t big_b  = rank_b + y0_b + a1_b + ybuf_b;
  if (x3_b > big_b) big_b = x3_b;
  char* big = carve(big_b);
  int*      rank  = (int*)big;
  float4*   y0    = (float4*)(big + rank_b);
  float4*   a1    = (float4*)(big + rank_b + y0_b);
  ushort16* ybufA = (ushort16*)(big + rank_b + y0_b + a1_b);   // layer-1 output y
  float*    x3    = (float*)big;   // written by layer-3 (which only reads ybufB) — safe alias

  const int* src = ei;
  const int* dst = ei + E;

  hipLaunchKernelGGL(k_setup, dim3((N+255)/256), dim3(256), 0, stream, deg, gsum, batch, N, G, gb);

  hipLaunchKernelGGL(k_count_rank, dim3((E+255)/256),   dim3(256), 0, stream, dst, E, deg, rank);
  hipLaunchKernelGGL(k_scan1,      dim3(B),             dim3(256), 0, stream, deg, N, offsets, bsum, dinv);
  hipLaunchKernelGGL(k_scan3b,     dim3(B),             dim3(256), 0, stream, offsets, N, bsum, B);
  hipLaunchKernelGGL(k_fill2,      dim3((E+N+255)/256), dim3(256), 0, stream, src, dst, E, N, offsets, rank, csr_src);

  hipLaunchKernelGGL(k_wprep2, dim3(16), dim3(256), 0, stream, W2, W3, wp2, wp3);

  // layer 1 (aggregate-first: tiny 3-wide gather)
  hipLaunchKernelGGL(k_prescale, dim3((N+255)/256), dim3(256), 0, stream, pos, dinv, y0, N);
  hipLaunchKernelGGL(k_agg3,     dim3((N+255)/256), dim3(256), 0, stream, y0, offsets, csr_src, dinv, a1, N);
  hipLaunchKernelGGL(k_dense1,   dim3(N),           dim3(128), 0, stream, a1, W1, b1, dinv, ybufA, N);

  // layer 2 (fused aggregate + MFMA, full gather parallelism)
  hipLaunchKernelGGL(k_aggdense<1>, dim3((N+15)/16), dim3(256), 0, stream,
                     ybufA, offsets, csr_src, dinv, wp2, b2, (float*)nullptr, ybufB, N);

  // layer 3 (fused), writes fp32 x3
  hipLaunchKernelGGL(k_aggdense<0>, dim3((N+15)/16), dim3(256), 0, stream,
                     ybufB, offsets, csr_src, dinv, wp3, b3, x3, (ushort16*)nullptr, N);

  hipLaunchKernelGGL(k_pool_partial, dim3(G, S), dim3(128), 0, stream, x3, gb, S, gsum);
  hipLaunchKernelGGL(k_head,         dim3(G),    dim3(64),  0, stream, gsum, gb, Wl1, bl1, Wl2, bl2, out);
}

// Round 10
// 262.200 us; speedup vs baseline: 1.2537x; 1.0264x over previous
//
#include <hip/hip_runtime.h>

#define H 128
#define LSTRIDE 136   // LDS row stride in bf16 elems: 272B, 16B-aligned, 2-way bank (free)
typedef unsigned int uint32;
typedef unsigned short ushort16;
typedef __attribute__((ext_vector_type(8))) short bf16x8;
typedef __attribute__((ext_vector_type(4))) float f32x4;

static __device__ __forceinline__ ushort16 f2bf(float f){
  uint32 u = __float_as_uint(f);
  uint32 r = (u + 0x7fff + ((u >> 16) & 1)) >> 16;   // RNE bf16 (finite values)
  return (ushort16)r;
}
static __device__ __forceinline__ float bflo(uint32 u){ return __uint_as_float(u << 16); }
static __device__ __forceinline__ float bfhi(uint32 u){ return __uint_as_float(u & 0xffff0000u); }

// fused setup: deg=0, gsum=0, graph boundaries gb[0..G]
__global__ __launch_bounds__(256) void k_setup(int* __restrict__ deg, float* __restrict__ gsum,
                                               const int* __restrict__ batch, int n, int G,
                                               int* __restrict__ gb){
  int i = blockIdx.x*256 + threadIdx.x;
  if (i < n) deg[i] = 0;
  if (i < G*H) gsum[i] = 0.f;
  if (i <= G){
    int lo = 0, hi = n;
    while (lo < hi){ int m = (lo + hi) >> 1; if (batch[m] < i) lo = m + 1; else hi = m; }
    gb[i] = lo;
  }
}

// rank[e] = position of edge e within its dst bucket; deg counts real in-edges
__global__ __launch_bounds__(256) void k_count_rank(const int* __restrict__ dst, int E,
                                                    int* __restrict__ deg, int* __restrict__ rank){
  int i = blockIdx.x*256 + threadIdx.x;
  if (i < E) rank[i] = atomicAdd(&deg[dst[i]], 1);
}

// ---- scan of (deg+1) -> block-local offsets, block totals to bsum, dinv ----
__global__ __launch_bounds__(256) void k_scan1(const int* __restrict__ deg, int n,
      int* __restrict__ offsets, int* __restrict__ bsum, float* __restrict__ dinv){
  __shared__ int sh[256];
  int b = blockIdx.x, t = threadIdx.x;
  int base = b*1024 + t*4;
  bool i0 = base+0 < n, i1 = base+1 < n, i2 = base+2 < n, i3 = base+3 < n;
  int d0=0,d1=0,d2=0,d3=0;
  if (i3){ int4 v = *(const int4*)&deg[base]; d0=v.x; d1=v.y; d2=v.z; d3=v.w; }
  else {
    if (i0) d0 = deg[base+0];
    if (i1) d1 = deg[base+1];
    if (i2) d2 = deg[base+2];
  }
  int e0 = i0? d0+1:0, e1 = i1? d1+1:0, e2 = i2? d2+1:0, e3 = i3? d3+1:0;   // +1 self-loop
  sh[t] = e0+e1+e2+e3;
  __syncthreads();
  for (int off=1; off<256; off<<=1){
    int v = sh[t];
    int add = (t>=off)? sh[t-off] : 0;
    __syncthreads();
    sh[t] = v+add;
    __syncthreads();
  }
  int o0 = (t==0)?0:sh[t-1];
  int o1 = o0+e0, o2 = o1+e1, o3 = o2+e2;
  if (i0){ offsets[base+0]=o0; dinv[base+0]=rsqrtf((float)(d0+1)); }
  if (i1){ offsets[base+1]=o1; dinv[base+1]=rsqrtf((float)(d1+1)); }
  if (i2){ offsets[base+2]=o2; dinv[base+2]=rsqrtf((float)(d2+1)); }
  if (i3){ offsets[base+3]=o3; dinv[base+3]=rsqrtf((float)(d3+1)); }
  if (t==255) bsum[b] = sh[255];
}

// add block prefix; prefix computed in-wave from bsum (requires B <= 64). Last block writes offsets[n].
__global__ __launch_bounds__(256) void k_scan3b(int* __restrict__ offsets, int n,
                                                const int* __restrict__ bsum, int B){
  __shared__ int sh[2];
  int b = blockIdx.x, t = threadIdx.x;
  if (t < 64){
    int v   = (t < B)? bsum[t] : 0;
    int pre = (t < b)? v : 0;
    int tot = v;
    for (int o=1; o<64; o<<=1){ pre += __shfl_xor(pre,o); tot += __shfl_xor(tot,o); }
    if (t == 0){ sh[0] = pre; sh[1] = tot; }
  }
  __syncthreads();
  int add = sh[0];
  int base = b*1024 + t*4;
  if (base+3 < n){
    int4 v = *(int4*)&offsets[base];
    v.x+=add; v.y+=add; v.z+=add; v.w+=add;
    *(int4*)&offsets[base] = v;
  } else {
    #pragma unroll
    for (int k=0;k<4;k++){ int i=base+k; if (i<n) offsets[i]+=add; }
  }
  if (b == B-1 && t == 255) offsets[n] = sh[1];
}

// atomic-free CSR fill: real edge e -> slot offsets[dst]+1+rank[e]; self-loop at slot offsets[i]
__global__ __launch_bounds__(256) void k_fill2(const int* __restrict__ src, const int* __restrict__ dst,
            int E, int n, const int* __restrict__ offsets, const int* __restrict__ rank,
            int* __restrict__ csr_src){
  int i = blockIdx.x*256 + threadIdx.x;
  if (i < E){
    csr_src[offsets[dst[i]] + 1 + rank[i]] = src[i];
  } else if (i < E + n){
    int j = i - E;
    csr_src[offsets[j]] = j;
  }
}

// y0[i] = dinv[i] * pos[i]  (padded float4)
__global__ __launch_bounds__(256) void k_prescale(const float* __restrict__ pos, const float* __restrict__ dinv,
                                                  float4* __restrict__ y0, int n){
  int i = blockIdx.x*256 + threadIdx.x;
  if (i < n){
    float d = dinv[i];
    y0[i] = make_float4(pos[3*i]*d, pos[3*i+1]*d, pos[3*i+2]*d, 0.f);
  }
}

// Fused layer 1: per node, a = dinv * sum_src y0[src] (3-wide gather), then
// y1[node,c] = bf16( dinv * relu(a . W1[:,c] + b1[c]) )  for all 128 cols.
// W1/b1 reads are wave-uniform -> scalar loads.
__global__ __launch_bounds__(256) void k_layer1(const float4* __restrict__ y0, const int* __restrict__ offsets,
      const int* __restrict__ csr_src, const float* __restrict__ dinv,
      const float* __restrict__ W1, const float* __restrict__ b1,
      ushort16* __restrict__ y1, int n){
  int node = blockIdx.x*256 + threadIdx.x;
  if (node >= n) return;
  int lo = offsets[node], hi = offsets[node+1];
  float x=0.f, y=0.f, z=0.f;
  int e = lo;
  for (; e+2 <= hi; e += 2){
    int s0 = csr_src[e], s1 = csr_src[e+1];
    float4 v0 = y0[s0], v1 = y0[s1];
    x += v0.x + v1.x; y += v0.y + v1.y; z += v0.z + v1.z;
  }
  if (e < hi){ float4 v = y0[csr_src[e]]; x += v.x; y += v.y; z += v.z; }
  float dn = dinv[node];
  x *= dn; y *= dn; z *= dn;
  ushort16* rowp = &y1[(size_t)node*H];
  for (int c8 = 0; c8 < 16; c8++){
    float4 wa0 = *(const float4*)&W1[c8*8];
    float4 wa1 = *(const float4*)&W1[c8*8+4];
    float4 wb0 = *(const float4*)&W1[H + c8*8];
    float4 wb1 = *(const float4*)&W1[H + c8*8+4];
    float4 wc0 = *(const float4*)&W1[2*H + c8*8];
    float4 wc1 = *(const float4*)&W1[2*H + c8*8+4];
    float4 bb0 = *(const float4*)&b1[c8*8];
    float4 bb1 = *(const float4*)&b1[c8*8+4];
    float o0 = fmaxf(x*wa0.x + y*wb0.x + z*wc0.x + bb0.x, 0.f) * dn;
    float o1 = fmaxf(x*wa0.y + y*wb0.y + z*wc0.y + bb0.y, 0.f) * dn;
    float o2 = fmaxf(x*wa0.z + y*wb0.z + z*wc0.z + bb0.z, 0.f) * dn;
    float o3 = fmaxf(x*wa0.w + y*wb0.w + z*wc0.w + bb0.w, 0.f) * dn;
    float o4 = fmaxf(x*wa1.x + y*wb1.x + z*wc1.x + bb1.x, 0.f) * dn;
    float o5 = fmaxf(x*wa1.y + y*wb1.y + z*wc1.y + bb1.y, 0.f) * dn;
    float o6 = fmaxf(x*wa1.z + y*wb1.z + z*wc1.z + bb1.z, 0.f) * dn;
    float o7 = fmaxf(x*wa1.w + y*wb1.w + z*wc1.w + bb1.w, 0.f) * dn;
    uint4 o;
    o.x = (uint32)f2bf(o0) | ((uint32)f2bf(o1) << 16);
    o.y = (uint32)f2bf(o2) | ((uint32)f2bf(o3) << 16);
    o.z = (uint32)f2bf(o4) | ((uint32)f2bf(o5) << 16);
    o.w = (uint32)f2bf(o6) | ((uint32)f2bf(o7) << 16);
    *(uint4*)&rowp[c8*8] = o;
  }
}

// prep W2+W3 (each K=128 x N=128, row-major fp32) into MFMA B-fragment order, bf16
__global__ __launch_bounds__(256) void k_wprep2(const float* __restrict__ W2, const float* __restrict__ W3,
                                                ushort16* __restrict__ wp2, ushort16* __restrict__ wp3){
  int gid = blockIdx.x*256 + threadIdx.x;   // 4096 threads total
  const float* W = (gid < 2048) ? W2 : W3;
  ushort16* wp   = (gid < 2048) ? wp2 : wp3;
  int tid = gid & 2047;
  int frag = tid >> 6, lane = tid & 63;
  int kt = frag >> 3, ct = frag & 7;
  int m = lane & 15, quad = lane >> 4;
  const float* wrow = &W[(kt*32 + quad*8)*H + ct*16 + m];
  ushort16 vals[8];
  #pragma unroll
  for (int j = 0; j < 8; j++) vals[j] = f2bf(wrow[j*H]);
  uint4 o;
  o.x = (uint32)vals[0] | ((uint32)vals[1] << 16);
  o.y = (uint32)vals[2] | ((uint32)vals[3] << 16);
  o.z = (uint32)vals[4] | ((uint32)vals[5] << 16);
  o.w = (uint32)vals[6] | ((uint32)vals[7] << 16);
  *(uint4*)&wp[(size_t)tid*8] = o;
}

// Fused aggregate + MFMA dense (full gather parallelism: 16 nodes/block, 16 lanes/node, one pass).
// POOL=0: yout[node,col] = bf16(dinv * relu(aW+b))  (layer 2)
// POOL=1: relu(aW+b) accumulated into gsum[graph,col] via LDS tile + segmented atomicAdd (layer 3 + mean-pool numerator)
template<int POOL>
__global__ __launch_bounds__(256) void k_aggdense(const ushort16* __restrict__ y, const int* __restrict__ offsets,
      const int* __restrict__ csr_src, const float* __restrict__ dinv, const ushort16* __restrict__ wp,
      const float* __restrict__ bias,
      ushort16* __restrict__ yout, const int* __restrict__ batch, float* __restrict__ gsum, int n){
  __shared__ unsigned short As[16*LSTRIDE];        // 4352 B
  __shared__ float pool[POOL ? 16*H : 1];          // 8 KB (POOL only)
  __shared__ int   sbatch[POOL ? 16 : 1];
  int tid = threadIdx.x;
  int node16 = blockIdx.x*16;
  int nl = tid >> 4;                 // local node 0..15
  int node = node16 + nl;
  int f8 = (tid & 15) * 8;

  if (POOL && tid < 16) sbatch[tid] = (node16 + tid < n) ? batch[node16 + tid] : -1;

  // ---- phase A: aggregate (identical parallelism to standalone agg128) ----
  float a0=0,a1=0,a2=0,a3=0,a4=0,a5=0,a6=0,a7=0;
  float dn = 0.f;
  #define ADDU(u) { a0+=bflo(u.x); a1+=bfhi(u.x); a2+=bflo(u.y); a3+=bfhi(u.y); \
                    a4+=bflo(u.z); a5+=bfhi(u.z); a6+=bflo(u.w); a7+=bfhi(u.w); }
  if (node < n){
    int lo = offsets[node], hi = offsets[node+1];
    int e = lo;
    for (; e+8 <= hi; e += 8){
      int s0=csr_src[e],   s1=csr_src[e+1], s2=csr_src[e+2], s3=csr_src[e+3];
      int s4=csr_src[e+4], s5=csr_src[e+5], s6=csr_src[e+6], s7=csr_src[e+7];
      uint4 u0 = *(const uint4*)&y[(size_t)s0*H + f8];
      uint4 u1 = *(const uint4*)&y[(size_t)s1*H + f8];
      uint4 u2 = *(const uint4*)&y[(size_t)s2*H + f8];
      uint4 u3 = *(const uint4*)&y[(size_t)s3*H + f8];
      uint4 u4 = *(const uint4*)&y[(size_t)s4*H + f8];
      uint4 u5 = *(const uint4*)&y[(size_t)s5*H + f8];
      uint4 u6 = *(const uint4*)&y[(size_t)s6*H + f8];
      uint4 u7 = *(const uint4*)&y[(size_t)s7*H + f8];
      ADDU(u0); ADDU(u1); ADDU(u2); ADDU(u3);
      ADDU(u4); ADDU(u5); ADDU(u6); ADDU(u7);
    }
    for (; e < hi; e++){
      int s = csr_src[e];
      uint4 u = *(const uint4*)&y[(size_t)s*H + f8];
      ADDU(u);
    }
    dn = dinv[node];
  }
  #undef ADDU
  uint4 o;
  o.x = (uint32)f2bf(a0*dn) | ((uint32)f2bf(a1*dn) << 16);
  o.y = (uint32)f2bf(a2*dn) | ((uint32)f2bf(a3*dn) << 16);
  o.z = (uint32)f2bf(a4*dn) | ((uint32)f2bf(a5*dn) << 16);
  o.w = (uint32)f2bf(a6*dn) | ((uint32)f2bf(a7*dn) << 16);
  *(uint4*)&As[nl*LSTRIDE + f8] = o;
  __syncthreads();

  // ---- phase B: MFMA — wave w handles col-tiles {2w, 2w+1} over the 16 staged rows ----
  int wave = tid >> 6;
  int lane = tid & 63;
  int m = lane & 15, quad = lane >> 4;
  f32x4 acc0 = {0.f,0.f,0.f,0.f}, acc1 = {0.f,0.f,0.f,0.f};
  int ct0 = wave*2, ct1 = wave*2 + 1;
  #pragma unroll
  for (int kt = 0; kt < 4; kt++){
    bf16x8 af = *(const bf16x8*)&As[m*LSTRIDE + kt*32 + quad*8];
    bf16x8 b0 = *(const bf16x8*)&wp[(size_t)((kt*8+ct0)*64 + lane)*8];
    bf16x8 b1 = *(const bf16x8*)&wp[(size_t)((kt*8+ct1)*64 + lane)*8];
    acc0 = __builtin_amdgcn_mfma_f32_16x16x32_bf16(af, b0, acc0, 0, 0, 0);
    acc1 = __builtin_amdgcn_mfma_f32_16x16x32_bf16(af, b1, acc1, 0, 0, 0);
  }
  // C/D layout: col = ct*16 + m, row (in tile) = quad*4 + r
  #pragma unroll
  for (int j = 0; j < 2; j++){
    int ct = wave*2 + j;
    int col = ct*16 + m;
    float bv = bias[col];
    f32x4 ac = j ? acc1 : acc0;
    #pragma unroll
    for (int r = 0; r < 4; r++){
      int rl = quad*4 + r;
      int orow = node16 + rl;
      if (orow < n){
        float v = fmaxf(ac[r] + bv, 0.f);
        if (POOL) pool[rl*H + col] = v;                               // one lane per (row,col): plain store
        else      yout[(size_t)orow*H + col] = f2bf(v * dinv[orow]);
      }
    }
  }
  if (POOL){
    __syncthreads();
    if (tid < H){
      int col = tid;
      float run = 0.f; int gprev = -1;
      for (int r = 0; r < 16; r++){
        int g = sbatch[r];
        if (g < 0) break;            // tail rows only
        if (g != gprev){
          if (gprev >= 0) atomicAdd(&gsum[gprev*H + col], run);
          run = 0.f; gprev = g;
        }
        run += pool[r*H + col];
      }
      if (gprev >= 0) atomicAdd(&gsum[gprev*H + col], run);
    }
  }
}

// MLP head: relu((gsum/cnt) @ Wl1 + bl1) @ Wl2 + bl2
__global__ __launch_bounds__(64) void k_head(const float* __restrict__ gsum, const int* __restrict__ gb,
            const float* __restrict__ Wl1, const float* __restrict__ bl1,
            const float* __restrict__ Wl2, const float* __restrict__ bl2,
            float* __restrict__ out){
  int g = blockIdx.x;
  int t = threadIdx.x;
  __shared__ float gs[H];
  __shared__ float h1[64];
  float inv = 1.f / fmaxf((float)(gb[g+1] - gb[g]), 1.f);
  gs[t]      = gsum[g*H + t]      * inv;
  gs[64 + t] = gsum[g*H + 64 + t] * inv;
  __syncthreads();
  float acc = bl1[t];
  for (int k = 0; k < H; k++) acc += gs[k] * Wl1[k*64 + t];
  h1[t] = fmaxf(acc, 0.f);
  __syncthreads();
  if (t < 10){
    float o = bl2[t];
    for (int j = 0; j < 64; j++) o += h1[j] * Wl2[j*10 + t];
    out[g*10 + t] = o;
  }
}

extern "C" void kernel_launch(void* const* d_in, const int* in_sizes, int n_in,
                              void* d_out, int out_size, void* d_ws, size_t ws_size,
                              hipStream_t stream){
  const float* pos = (const float*)d_in[0];
  const int*  ei   = (const int*)d_in[1];
  const int*  batch= (const int*)d_in[2];
  const float* W1 = (const float*)d_in[3];
  const float* b1 = (const float*)d_in[4];
  const float* W2 = (const float*)d_in[5];
  const float* b2 = (const float*)d_in[6];
  const float* W3 = (const float*)d_in[7];
  const float* b3 = (const float*)d_in[8];
  const float* Wl1 = (const float*)d_in[9];
  const float* bl1 = (const float*)d_in[10];
  const float* Wl2 = (const float*)d_in[11];
  const float* bl2 = (const float*)d_in[12];
  float* out = (float*)d_out;

  int N = in_sizes[0] / 3;     // 50000
  int E = in_sizes[1] / 2;     // 800000
  int G = out_size / 10;       // 64
  int B = (N + 1023) / 1024;   // 49, must be <= 64 for k_scan3b

  // workspace carve (~34 MB, no aliasing needed)
  char* p = (char*)d_ws;
  auto carve = [&](size_t bytes)->char* { char* q = p; p += (bytes + 255) & ~(size_t)255; return q; };
  int*      deg     = (int*)     carve(sizeof(int)    * (size_t)N);
  int*      offsets = (int*)     carve(sizeof(int)    * (size_t)(N+1));
  float*    dinv    = (float*)   carve(sizeof(float)  * (size_t)N);
  int*      bsum    = (int*)     carve(sizeof(int)    * 256);
  int*      gb      = (int*)     carve(sizeof(int)    * (size_t)(G+1));
  float*    gsum    = (float*)   carve(sizeof(float)  * (size_t)G * H);
  int*      csr_src = (int*)     carve(sizeof(int)    * (size_t)(E+N));
  int*      rank    = (int*)     carve(sizeof(int)    * (size_t)E);
  float4*   y0      = (float4*)  carve(sizeof(float4) * (size_t)N);
  ushort16* ybufA   = (ushort16*)carve(sizeof(ushort16) * (size_t)N * H);
  ushort16* ybufB   = (ushort16*)carve(sizeof(ushort16) * (size_t)N * H);
  ushort16* wp2     = (ushort16*)carve(sizeof(ushort16) * 16384);
  ushort16* wp3     = (ushort16*)carve(sizeof(ushort16) * 16384);

  const int* src = ei;
  const int* dst = ei + E;

  hipLaunchKernelGGL(k_setup, dim3((N+255)/256), dim3(256), 0, stream, deg, gsum, batch, N, G, gb);

  hipLaunchKernelGGL(k_count_rank, dim3((E+255)/256),   dim3(256), 0, stream, dst, E, deg, rank);
  hipLaunchKernelGGL(k_scan1,      dim3(B),             dim3(256), 0, stream, deg, N, offsets, bsum, dinv);
  hipLaunchKernelGGL(k_scan3b,     dim3(B),             dim3(256), 0, stream, offsets, N, bsum, B);
  hipLaunchKernelGGL(k_fill2,      dim3((E+N+255)/256), dim3(256), 0, stream, src, dst, E, N, offsets, rank, csr_src);

  hipLaunchKernelGGL(k_wprep2, dim3(16), dim3(256), 0, stream, W2, W3, wp2, wp3);

  // layer 1 (aggregate-first 3-wide gather + fused 3->128 dense)
  hipLaunchKernelGGL(k_prescale, dim3((N+255)/256), dim3(256), 0, stream, pos, dinv, y0, N);
  hipLaunchKernelGGL(k_layer1,   dim3((N+255)/256), dim3(256), 0, stream, y0, offsets, csr_src, dinv, W1, b1, ybufA, N);

  // layer 2 (fused aggregate + MFMA, bf16 y out)
  hipLaunchKernelGGL(k_aggdense<0>, dim3((N+15)/16), dim3(256), 0, stream,
                     ybufA, offsets, csr_src, dinv, wp2, b2, ybufB, (const int*)nullptr, (float*)nullptr, N);

  // layer 3 (fused aggregate + MFMA + mean-pool numerator into gsum)
  hipLaunchKernelGGL(k_aggdense<1>, dim3((N+15)/16), dim3(256), 0, stream,
                     ybufB, offsets, csr_src, dinv, wp3, b3, (ushort16*)nullptr, batch, gsum, N);

  hipLaunchKernelGGL(k_head, dim3(G), dim3(64), 0, stream, gsum, gb, Wl1, bl1, Wl2, bl2, out);
}

// Round 11
// 252.627 us; speedup vs baseline: 1.3012x; 1.0379x over previous
//
#include <hip/hip_runtime.h>

#define H 128
#define LSTRIDE 136   // LDS row stride in bf16 elems: 272B, 16B-aligned, 2-way bank (free)
#define PSTR 132      // pool stride in floats: rl*132 -> bank offset rl*4, 2-way (free)
typedef unsigned int uint32;
typedef unsigned short ushort16;
typedef __attribute__((ext_vector_type(8))) short bf16x8;
typedef __attribute__((ext_vector_type(4))) float f32x4;

static __device__ __forceinline__ ushort16 f2bf(float f){
  uint32 u = __float_as_uint(f);
  uint32 r = (u + 0x7fff + ((u >> 16) & 1)) >> 16;   // RNE bf16 (finite values)
  return (ushort16)r;
}
static __device__ __forceinline__ float bflo(uint32 u){ return __uint_as_float(u << 16); }
static __device__ __forceinline__ float bfhi(uint32 u){ return __uint_as_float(u & 0xffff0000u); }

// fused setup: deg=0, gsum=0, gb[0..G]; last 16 blocks also prep W2/W3 into MFMA B-frag bf16
__global__ __launch_bounds__(256) void k_setup(int* __restrict__ deg, float* __restrict__ gsum,
                                               const int* __restrict__ batch, int n, int G,
                                               int* __restrict__ gb, int SB,
                                               const float* __restrict__ W2, const float* __restrict__ W3,
                                               ushort16* __restrict__ wp2, ushort16* __restrict__ wp3){
  int b = blockIdx.x;
  if (b < SB){
    int i = b*256 + threadIdx.x;
    if (i < n) deg[i] = 0;
    if (i < G*H) gsum[i] = 0.f;
    if (i <= G){
      int lo = 0, hi = n;
      while (lo < hi){ int m = (lo + hi) >> 1; if (batch[m] < i) lo = m + 1; else hi = m; }
      gb[i] = lo;
    }
  } else {
    int gid = (b - SB)*256 + threadIdx.x;   // 0..4095
    const float* W = (gid < 2048) ? W2 : W3;
    ushort16* wp   = (gid < 2048) ? wp2 : wp3;
    int tid = gid & 2047;
    int frag = tid >> 6, lane = tid & 63;
    int kt = frag >> 3, ct = frag & 7;
    int m = lane & 15, quad = lane >> 4;
    const float* wrow = &W[(kt*32 + quad*8)*H + ct*16 + m];
    ushort16 vals[8];
    #pragma unroll
    for (int j = 0; j < 8; j++) vals[j] = f2bf(wrow[j*H]);
    uint4 o;
    o.x = (uint32)vals[0] | ((uint32)vals[1] << 16);
    o.y = (uint32)vals[2] | ((uint32)vals[3] << 16);
    o.z = (uint32)vals[4] | ((uint32)vals[5] << 16);
    o.w = (uint32)vals[6] | ((uint32)vals[7] << 16);
    *(uint4*)&wp[(size_t)tid*8] = o;
  }
}

// rank[e] = position of edge e within its dst bucket (ushort: max deg << 65536)
__global__ __launch_bounds__(256) void k_count_rank(const int* __restrict__ dst, int E,
                                                    int* __restrict__ deg, unsigned short* __restrict__ rank){
  int i = blockIdx.x*256 + threadIdx.x;
  if (i < E) rank[i] = (unsigned short)atomicAdd(&deg[dst[i]], 1);
}

// ---- scan of (deg+1) -> block-local offsets, block totals to bsum, dinv ----
__global__ __launch_bounds__(256) void k_scan1(const int* __restrict__ deg, int n,
      int* __restrict__ offsets, int* __restrict__ bsum, float* __restrict__ dinv){
  __shared__ int sh[256];
  int b = blockIdx.x, t = threadIdx.x;
  int base = b*1024 + t*4;
  bool i0 = base+0 < n, i1 = base+1 < n, i2 = base+2 < n, i3 = base+3 < n;
  int d0=0,d1=0,d2=0,d3=0;
  if (i3){ int4 v = *(const int4*)&deg[base]; d0=v.x; d1=v.y; d2=v.z; d3=v.w; }
  else {
    if (i0) d0 = deg[base+0];
    if (i1) d1 = deg[base+1];
    if (i2) d2 = deg[base+2];
  }
  int e0 = i0? d0+1:0, e1 = i1? d1+1:0, e2 = i2? d2+1:0, e3 = i3? d3+1:0;   // +1 self-loop
  sh[t] = e0+e1+e2+e3;
  __syncthreads();
  for (int off=1; off<256; off<<=1){
    int v = sh[t];
    int add = (t>=off)? sh[t-off] : 0;
    __syncthreads();
    sh[t] = v+add;
    __syncthreads();
  }
  int o0 = (t==0)?0:sh[t-1];
  int o1 = o0+e0, o2 = o1+e1, o3 = o2+e2;
  if (i0){ offsets[base+0]=o0; dinv[base+0]=rsqrtf((float)(d0+1)); }
  if (i1){ offsets[base+1]=o1; dinv[base+1]=rsqrtf((float)(d1+1)); }
  if (i2){ offsets[base+2]=o2; dinv[base+2]=rsqrtf((float)(d2+1)); }
  if (i3){ offsets[base+3]=o3; dinv[base+3]=rsqrtf((float)(d3+1)); }
  if (t==255) bsum[b] = sh[255];
}

// add block prefix; prefix computed in-wave from bsum (requires B <= 64). Last block writes offsets[n].
__global__ __launch_bounds__(256) void k_scan3b(int* __restrict__ offsets, int n,
                                                const int* __restrict__ bsum, int B){
  __shared__ int sh[2];
  int b = blockIdx.x, t = threadIdx.x;
  if (t < 64){
    int v   = (t < B)? bsum[t] : 0;
    int pre = (t < b)? v : 0;
    int tot = v;
    for (int o=1; o<64; o<<=1){ pre += __shfl_xor(pre,o); tot += __shfl_xor(tot,o); }
    if (t == 0){ sh[0] = pre; sh[1] = tot; }
  }
  __syncthreads();
  int add = sh[0];
  int base = b*1024 + t*4;
  if (base+3 < n){
    int4 v = *(int4*)&offsets[base];
    v.x+=add; v.y+=add; v.z+=add; v.w+=add;
    *(int4*)&offsets[base] = v;
  } else {
    #pragma unroll
    for (int k=0;k<4;k++){ int i=base+k; if (i<n) offsets[i]+=add; }
  }
  if (b == B-1 && t == 255) offsets[n] = sh[1];
}

// atomic-free CSR fill (ushort payload): edge e -> slot offsets[dst]+1+rank[e]; self-loop at offsets[i]
__global__ __launch_bounds__(256) void k_fill2(const int* __restrict__ src, const int* __restrict__ dst,
            int E, int n, const int* __restrict__ offsets, const unsigned short* __restrict__ rank,
            unsigned short* __restrict__ csr_src){
  int i = blockIdx.x*256 + threadIdx.x;
  if (i < E){
    csr_src[offsets[dst[i]] + 1 + rank[i]] = (unsigned short)src[i];
  } else if (i < E + n){
    int j = i - E;
    csr_src[offsets[j]] = (unsigned short)j;
  }
}

// y0[i] = dinv[i] * pos[i]  (padded float4)
__global__ __launch_bounds__(256) void k_prescale(const float* __restrict__ pos, const float* __restrict__ dinv,
                                                  float4* __restrict__ y0, int n){
  int i = blockIdx.x*256 + threadIdx.x;
  if (i < n){
    float d = dinv[i];
    y0[i] = make_float4(pos[3*i]*d, pos[3*i+1]*d, pos[3*i+2]*d, 0.f);
  }
}

// Fused layer 1: per node, a = dinv * sum_src y0[src] (3-wide gather), then
// y1[node,c] = bf16( dinv * relu(a . W1[:,c] + b1[c]) ) for all 128 cols (W1/b1 wave-uniform).
__global__ __launch_bounds__(256) void k_layer1(const float4* __restrict__ y0, const int* __restrict__ offsets,
      const unsigned short* __restrict__ csr_src, const float* __restrict__ dinv,
      const float* __restrict__ W1, const float* __restrict__ b1,
      ushort16* __restrict__ y1, int n){
  int node = blockIdx.x*256 + threadIdx.x;
  if (node >= n) return;
  int lo = offsets[node], hi = offsets[node+1];
  float x=0.f, y=0.f, z=0.f;
  int e = lo;
  for (; e+2 <= hi; e += 2){
    int s0 = csr_src[e], s1 = csr_src[e+1];
    float4 v0 = y0[s0], v1 = y0[s1];
    x += v0.x + v1.x; y += v0.y + v1.y; z += v0.z + v1.z;
  }
  if (e < hi){ float4 v = y0[csr_src[e]]; x += v.x; y += v.y; z += v.z; }
  float dn = dinv[node];
  x *= dn; y *= dn; z *= dn;
  ushort16* rowp = &y1[(size_t)node*H];
  for (int c8 = 0; c8 < 16; c8++){
    float4 wa0 = *(const float4*)&W1[c8*8];
    float4 wa1 = *(const float4*)&W1[c8*8+4];
    float4 wb0 = *(const float4*)&W1[H + c8*8];
    float4 wb1 = *(const float4*)&W1[H + c8*8+4];
    float4 wc0 = *(const float4*)&W1[2*H + c8*8];
    float4 wc1 = *(const float4*)&W1[2*H + c8*8+4];
    float4 bb0 = *(const float4*)&b1[c8*8];
    float4 bb1 = *(const float4*)&b1[c8*8+4];
    float o0 = fmaxf(x*wa0.x + y*wb0.x + z*wc0.x + bb0.x, 0.f) * dn;
    float o1 = fmaxf(x*wa0.y + y*wb0.y + z*wc0.y + bb0.y, 0.f) * dn;
    float o2 = fmaxf(x*wa0.z + y*wb0.z + z*wc0.z + bb0.z, 0.f) * dn;
    float o3 = fmaxf(x*wa0.w + y*wb0.w + z*wc0.w + bb0.w, 0.f) * dn;
    float o4 = fmaxf(x*wa1.x + y*wb1.x + z*wc1.x + bb1.x, 0.f) * dn;
    float o5 = fmaxf(x*wa1.y + y*wb1.y + z*wc1.y + bb1.y, 0.f) * dn;
    float o6 = fmaxf(x*wa1.z + y*wb1.z + z*wc1.z + bb1.z, 0.f) * dn;
    float o7 = fmaxf(x*wa1.w + y*wb1.w + z*wc1.w + bb1.w, 0.f) * dn;
    uint4 o;
    o.x = (uint32)f2bf(o0) | ((uint32)f2bf(o1) << 16);
    o.y = (uint32)f2bf(o2) | ((uint32)f2bf(o3) << 16);
    o.z = (uint32)f2bf(o4) | ((uint32)f2bf(o5) << 16);
    o.w = (uint32)f2bf(o6) | ((uint32)f2bf(o7) << 16);
    *(uint4*)&rowp[c8*8] = o;
  }
}

// Fused aggregate + MFMA dense (full gather parallelism: 16 nodes/block, 16 lanes/node, one pass).
// POOL=0: yout tile staged in LDS then coalesced 16B/lane bf16 stores (layer 2)
// POOL=1: relu(aW+b) -> LDS tile -> parallel segmented atomicAdd into gsum (layer 3 + pool numerator)
template<int POOL>
__global__ __launch_bounds__(256) void k_aggdense(const ushort16* __restrict__ y, const int* __restrict__ offsets,
      const unsigned short* __restrict__ csr_src, const float* __restrict__ dinv, const ushort16* __restrict__ wp,
      const float* __restrict__ bias,
      ushort16* __restrict__ yout, const int* __restrict__ batch, float* __restrict__ gsum, int n){
  __shared__ unsigned short As[16*LSTRIDE];          // 4352 B
  __shared__ float pool[POOL ? 16*PSTR : 1];         // 8448 B (POOL only)
  __shared__ unsigned short outs[POOL ? 1 : 16*PSTR];// 4224 B (non-POOL: staged bf16 out tile)
  __shared__ int sbatch[POOL ? 16 : 1];
  int tid = threadIdx.x;
  int node16 = blockIdx.x*16;
  int nl = tid >> 4;                 // local node 0..15
  int node = node16 + nl;
  int f8 = (tid & 15) * 8;

  if (POOL && tid < 16) sbatch[tid] = (node16 + tid < n) ? batch[node16 + tid] : -1;

  // ---- phase A: aggregate (identical parallelism to standalone agg128) ----
  float a0=0,a1=0,a2=0,a3=0,a4=0,a5=0,a6=0,a7=0;
  float dn = 0.f;
  #define ADDU(u) { a0+=bflo(u.x); a1+=bfhi(u.x); a2+=bflo(u.y); a3+=bfhi(u.y); \
                    a4+=bflo(u.z); a5+=bfhi(u.z); a6+=bflo(u.w); a7+=bfhi(u.w); }
  if (node < n){
    int lo = offsets[node], hi = offsets[node+1];
    int e = lo;
    for (; e+8 <= hi; e += 8){
      int s0=csr_src[e],   s1=csr_src[e+1], s2=csr_src[e+2], s3=csr_src[e+3];
      int s4=csr_src[e+4], s5=csr_src[e+5], s6=csr_src[e+6], s7=csr_src[e+7];
      uint4 u0 = *(const uint4*)&y[(size_t)s0*H + f8];
      uint4 u1 = *(const uint4*)&y[(size_t)s1*H + f8];
      uint4 u2 = *(const uint4*)&y[(size_t)s2*H + f8];
      uint4 u3 = *(const uint4*)&y[(size_t)s3*H + f8];
      uint4 u4 = *(const uint4*)&y[(size_t)s4*H + f8];
      uint4 u5 = *(const uint4*)&y[(size_t)s5*H + f8];
      uint4 u6 = *(const uint4*)&y[(size_t)s6*H + f8];
      uint4 u7 = *(const uint4*)&y[(size_t)s7*H + f8];
      ADDU(u0); ADDU(u1); ADDU(u2); ADDU(u3);
      ADDU(u4); ADDU(u5); ADDU(u6); ADDU(u7);
    }
    for (; e < hi; e++){
      int s = csr_src[e];
      uint4 u = *(const uint4*)&y[(size_t)s*H + f8];
      ADDU(u);
    }
    dn = dinv[node];
  }
  #undef ADDU
  uint4 o;
  o.x = (uint32)f2bf(a0*dn) | ((uint32)f2bf(a1*dn) << 16);
  o.y = (uint32)f2bf(a2*dn) | ((uint32)f2bf(a3*dn) << 16);
  o.z = (uint32)f2bf(a4*dn) | ((uint32)f2bf(a5*dn) << 16);
  o.w = (uint32)f2bf(a6*dn) | ((uint32)f2bf(a7*dn) << 16);
  *(uint4*)&As[nl*LSTRIDE + f8] = o;
  __syncthreads();

  // ---- phase B: MFMA — wave w handles col-tiles {2w, 2w+1} over the 16 staged rows ----
  int wave = tid >> 6;
  int lane = tid & 63;
  int m = lane & 15, quad = lane >> 4;
  f32x4 acc0 = {0.f,0.f,0.f,0.f}, acc1 = {0.f,0.f,0.f,0.f};
  int ct0 = wave*2, ct1 = wave*2 + 1;
  #pragma unroll
  for (int kt = 0; kt < 4; kt++){
    bf16x8 af = *(const bf16x8*)&As[m*LSTRIDE + kt*32 + quad*8];
    bf16x8 b0 = *(const bf16x8*)&wp[(size_t)((kt*8+ct0)*64 + lane)*8];
    bf16x8 b1 = *(const bf16x8*)&wp[(size_t)((kt*8+ct1)*64 + lane)*8];
    acc0 = __builtin_amdgcn_mfma_f32_16x16x32_bf16(af, b0, acc0, 0, 0, 0);
    acc1 = __builtin_amdgcn_mfma_f32_16x16x32_bf16(af, b1, acc1, 0, 0, 0);
  }
  // C/D layout: col = ct*16 + m, row (in tile) = quad*4 + r
  #pragma unroll
  for (int j = 0; j < 2; j++){
    int ct = wave*2 + j;
    int col = ct*16 + m;
    float bv = bias[col];
    f32x4 ac = j ? acc1 : acc0;
    #pragma unroll
    for (int r = 0; r < 4; r++){
      int rl = quad*4 + r;
      int orow = node16 + rl;
      if (orow < n){
        float v = fmaxf(ac[r] + bv, 0.f);
        if (POOL) pool[rl*PSTR + col] = v;                            // one lane per (row,col)
        else      outs[rl*PSTR + col] = f2bf(v * dinv[orow]);
      }
    }
  }
  __syncthreads();
  if (POOL){
    // parallel segmented tail: 256 threads = 128 cols x 2 row-halves
    int col = tid & 127;
    int half = tid >> 7;
    float run = 0.f; int gprev = -1;
    for (int r = half*8; r < half*8 + 8; r++){
      int g = sbatch[r];
      if (g < 0) break;            // tail rows only
      if (g != gprev){
        if (gprev >= 0) atomicAdd(&gsum[gprev*H + col], run);
        run = 0.f; gprev = g;
      }
      run += pool[r*PSTR + col];
    }
    if (gprev >= 0) atomicAdd(&gsum[gprev*H + col], run);
  } else {
    // coalesced store: thread t writes row t>>4, 8 bf16 at (t&15)*8
    int row = tid >> 4;
    int orow = node16 + row;
    if (orow < n){
      const unsigned short* sp = &outs[row*PSTR + f8];
      uint4 v;
      v.x = (uint32)sp[0] | ((uint32)sp[1] << 16);
      v.y = (uint32)sp[2] | ((uint32)sp[3] << 16);
      v.z = (uint32)sp[4] | ((uint32)sp[5] << 16);
      v.w = (uint32)sp[6] | ((uint32)sp[7] << 16);
      *(uint4*)&yout[(size_t)orow*H + f8] = v;
    }
  }
}

// MLP head: relu((gsum/cnt) @ Wl1 + bl1) @ Wl2 + bl2
__global__ __launch_bounds__(64) void k_head(const float* __restrict__ gsum, const int* __restrict__ gb,
            const float* __restrict__ Wl1, const float* __restrict__ bl1,
            const float* __restrict__ Wl2, const float* __restrict__ bl2,
            float* __restrict__ out){
  int g = blockIdx.x;
  int t = threadIdx.x;
  __shared__ float gs[H];
  __shared__ float h1[64];
  float inv = 1.f / fmaxf((float)(gb[g+1] - gb[g]), 1.f);
  gs[t]      = gsum[g*H + t]      * inv;
  gs[64 + t] = gsum[g*H + 64 + t] * inv;
  __syncthreads();
  float acc = bl1[t];
  for (int k = 0; k < H; k++) acc += gs[k] * Wl1[k*64 + t];
  h1[t] = fmaxf(acc, 0.f);
  __syncthreads();
  if (t < 10){
    float o = bl2[t];
    for (int j = 0; j < 64; j++) o += h1[j] * Wl2[j*10 + t];
    out[g*10 + t] = o;
  }
}

extern "C" void kernel_launch(void* const* d_in, const int* in_sizes, int n_in,
                              void* d_out, int out_size, void* d_ws, size_t ws_size,
                              hipStream_t stream){
  const float* pos = (const float*)d_in[0];
  const int*  ei   = (const int*)d_in[1];
  const int*  batch= (const int*)d_in[2];
  const float* W1 = (const float*)d_in[3];
  const float* b1 = (const float*)d_in[4];
  const float* W2 = (const float*)d_in[5];
  const float* b2 = (const float*)d_in[6];
  const float* W3 = (const float*)d_in[7];
  const float* b3 = (const float*)d_in[8];
  const float* Wl1 = (const float*)d_in[9];
  const float* bl1 = (const float*)d_in[10];
  const float* Wl2 = (const float*)d_in[11];
  const float* bl2 = (const float*)d_in[12];
  float* out = (float*)d_out;

  int N = in_sizes[0] / 3;     // 50000 (< 65536 required for ushort CSR)
  int E = in_sizes[1] / 2;     // 800000
  int G = out_size / 10;       // 64
  int B = (N + 1023) / 1024;   // 49, must be <= 64 for k_scan3b
  int SB = (N + 255) / 256;    // setup blocks

  // workspace carve (~30 MB)
  char* p = (char*)d_ws;
  auto carve = [&](size_t bytes)->char* { char* q = p; p += (bytes + 255) & ~(size_t)255; return q; };
  int*            deg     = (int*)     carve(sizeof(int)    * (size_t)N);
  int*            offsets = (int*)     carve(sizeof(int)    * (size_t)(N+1));
  float*          dinv    = (float*)   carve(sizeof(float)  * (size_t)N);
  int*            bsum    = (int*)     carve(sizeof(int)    * 256);
  int*            gb      = (int*)     carve(sizeof(int)    * (size_t)(G+1));
  float*          gsum    = (float*)   carve(sizeof(float)  * (size_t)G * H);
  unsigned short* csr_src = (unsigned short*)carve(sizeof(unsigned short) * (size_t)(E+N));
  unsigned short* rank    = (unsigned short*)carve(sizeof(unsigned short) * (size_t)E);
  float4*         y0      = (float4*)  carve(sizeof(float4) * (size_t)N);
  ushort16*       ybufA   = (ushort16*)carve(sizeof(ushort16) * (size_t)N * H);
  ushort16*       ybufB   = (ushort16*)carve(sizeof(ushort16) * (size_t)N * H);
  ushort16*       wp2     = (ushort16*)carve(sizeof(ushort16) * 16384);
  ushort16*       wp3     = (ushort16*)carve(sizeof(ushort16) * 16384);

  const int* src = ei;
  const int* dst = ei + E;

  hipLaunchKernelGGL(k_setup, dim3(SB + 16), dim3(256), 0, stream,
                     deg, gsum, batch, N, G, gb, SB, W2, W3, wp2, wp3);

  hipLaunchKernelGGL(k_count_rank, dim3((E+255)/256),   dim3(256), 0, stream, dst, E, deg, rank);
  hipLaunchKernelGGL(k_scan1,      dim3(B),             dim3(256), 0, stream, deg, N, offsets, bsum, dinv);
  hipLaunchKernelGGL(k_scan3b,     dim3(B),             dim3(256), 0, stream, offsets, N, bsum, B);
  hipLaunchKernelGGL(k_fill2,      dim3((E+N+255)/256), dim3(256), 0, stream, src, dst, E, N, offsets, rank, csr_src);

  // layer 1 (aggregate-first 3-wide gather + fused 3->128 dense)
  hipLaunchKernelGGL(k_prescale, dim3((N+255)/256), dim3(256), 0, stream, pos, dinv, y0, N);
  hipLaunchKernelGGL(k_layer1,   dim3((N+255)/256), dim3(256), 0, stream, y0, offsets, csr_src, dinv, W1, b1, ybufA, N);

  // layer 2 (fused aggregate + MFMA, bf16 y out via LDS-staged coalesced store)
  hipLaunchKernelGGL(k_aggdense<0>, dim3((N+15)/16), dim3(256), 0, stream,
                     ybufA, offsets, csr_src, dinv, wp2, b2, ybufB, (const int*)nullptr, (float*)nullptr, N);

  // layer 3 (fused aggregate + MFMA + mean-pool numerator into gsum)
  hipLaunchKernelGGL(k_aggdense<1>, dim3((N+15)/16), dim3(256), 0, stream,
                     ybufB, offsets, csr_src, dinv, wp3, b3, (ushort16*)nullptr, batch, gsum, N);

  hipLaunchKernelGGL(k_head, dim3(G), dim3(64), 0, stream, gsum, gb, Wl1, bl1, Wl2, bl2, out);
}